// Round 3
// baseline (1993.883 us; speedup 1.0000x reference)
//
#include <hip/hip_runtime.h>

#define NN 50000
#define EE 600000
#define BB 64
#define CH 128
#define LL 3
#define NSB 196   // stats stage-1 blocks

typedef unsigned short u16;
typedef unsigned int u32;
typedef short s16x8 __attribute__((ext_vector_type(8)));
typedef float f32x4 __attribute__((ext_vector_type(4)));

__device__ __forceinline__ u16 f2b(float f) {
    u32 x = __float_as_uint(f);
    return (u16)((x + 0x7FFFu + ((x >> 16) & 1u)) >> 16);  // RNE f32->bf16
}

// ---------------------------------------------------------------------------
// y[dst] += x[src] over edges. One wave per edge, lane handles 2 channels.
// y is in d_ws (coarse-grained) -> HW f32 atomics are safe.
// ---------------------------------------------------------------------------
__global__ __launch_bounds__(256) void k_scatter(const float* __restrict__ x,
                                                 const int* __restrict__ ei,
                                                 float* __restrict__ y) {
    int gt = blockIdx.x * 256 + threadIdx.x;
    int wave = gt >> 6;
    int lane = gt & 63;
    int nw = (gridDim.x * 256) >> 6;
    for (int e = wave; e < EE; e += nw) {
        int src = ei[e];
        int dst = ei[EE + e];
        float2 v = *(const float2*)(x + (long)src * CH + lane * 2);
        float* yp = y + (long)dst * CH + lane * 2;
        unsafeAtomicAdd(yp, v.x);
        unsafeAtomicAdd(yp + 1, v.y);
    }
}

// ---------------------------------------------------------------------------
// Transpose + convert weights once: Wt[slot][n*128+k] = bf16(W[k][n])
// slots 0-2: convW1[l], 3-5: convW2[l], 6: recW1, 7: recW2, 8: recW3 (zero-pad)
// ---------------------------------------------------------------------------
__global__ __launch_bounds__(256) void k_transpose_all(
    const float* __restrict__ cW1, const float* __restrict__ cW2,
    const float* __restrict__ rW1, const float* __restrict__ rW2,
    const float* __restrict__ rW3, u16* __restrict__ Wt) {
    int idx = blockIdx.x * 256 + threadIdx.x;
    if (idx < 8 * 16384) {
        int slot = idx >> 14;
        int wi = idx & 16383;
        int k = wi >> 7, n = wi & 127;
        const float* src = slot < 3 ? cW1 + slot * 16384
                         : slot < 6 ? cW2 + (slot - 3) * 16384
                         : slot == 6 ? rW1 : rW2;
        Wt[slot * 16384 + n * 128 + k] = f2b(src[wi]);
    } else if (idx < 9 * 16384) {
        int j = idx - 8 * 16384;
        int n = j >> 7, k = j & 127;
        Wt[8 * 16384 + j] = (n < 4) ? f2b(rW3[k * 4 + n]) : (u16)0;
    }
}

// ---------------------------------------------------------------------------
// MFMA GEMM: C[M x ldc] = op(A)[M x 128] @ Wt^T + bias, K = 128, all I/O f32.
// BN: apply relu(scale*a+shift) while staging A.  RELU: relu on output.
// Block 256 = 4 waves, 128 rows/block, NT 16-col tiles.
// LDS XOR-swizzle: 16B chunk c of row r stored at chunk (c ^ (r&15)).
// A-frag: lane holds A[m=lane&15][k=quad*8+j]; B-frag: B[k=quad*8+j][n=lane&15]
// C/D: col=lane&15, row=quad*4+reg  (verified m89/m91).
// In-place safe: each block stages ALL its A rows to LDS before writing C,
// and blocks own disjoint row ranges.
// ---------------------------------------------------------------------------
template <int NT, bool BN, bool RELU>
__global__ __launch_bounds__(256) void k_gemm(
    const float* __restrict__ Ap, const u16* __restrict__ Wt,
    const float* __restrict__ bias, const float* __restrict__ scale,
    const float* __restrict__ shift, float* __restrict__ Cp, int M, int ldc) {
    __shared__ u16 sA[128 * CH];
    __shared__ u16 sB[NT * 16 * CH];
    const int tid = threadIdx.x;
    const int s = tid & 15;   // 8-element chunk index within a row
    const int rr = tid >> 4;  // row within each 16-row staging group
    const int r0 = blockIdx.x * 128;

    float sc[8], sh[8];
    if constexpr (BN) {
#pragma unroll
        for (int j = 0; j < 8; ++j) {
            sc[j] = scale[8 * s + j];
            sh[j] = shift[8 * s + j];
        }
    }

    // stage B (pre-transposed bf16 weights: row n holds W[:,n] contiguous in k)
#pragma unroll
    for (int it = 0; it < NT; ++it) {
        int n = it * 16 + rr;
        uint4 u = *(const uint4*)(Wt + n * CH + 8 * s);
        int phys = (s ^ (n & 15)) * 8;
        *(uint4*)(&sB[n * CH + phys]) = u;
    }
    // stage A (f32 -> bf16, optional fused BN+relu)
#pragma unroll
    for (int it = 0; it < 8; ++it) {
        int lr = it * 16 + rr;
        int gr = r0 + lr;
        union { u16 pk[8]; uint4 v; } uu;
        if (gr < M) {
            const float* Af = Ap + (long)gr * CH + 8 * s;
            float4 f0 = *(const float4*)Af;
            float4 f1 = *(const float4*)(Af + 4);
            float vj[8] = {f0.x, f0.y, f0.z, f0.w, f1.x, f1.y, f1.z, f1.w};
#pragma unroll
            for (int j = 0; j < 8; ++j) {
                float v = vj[j];
                if constexpr (BN) v = fmaxf(v * sc[j] + sh[j], 0.f);
                uu.pk[j] = f2b(v);
            }
        } else {
#pragma unroll
            for (int j = 0; j < 8; ++j) uu.pk[j] = 0;
        }
        int phys = (s ^ (lr & 15)) * 8;
        *(uint4*)(&sA[lr * CH + phys]) = uu.v;
    }
    __syncthreads();

    const int lane = tid & 63;
    const int wv = tid >> 6;
    const int quad = lane >> 4;
    const int l16 = lane & 15;

    f32x4 zero4 = {0.f, 0.f, 0.f, 0.f};
    f32x4 acc[2][NT];
#pragma unroll
    for (int m = 0; m < 2; ++m)
#pragma unroll
        for (int t = 0; t < NT; ++t) acc[m][t] = zero4;

    const u16* pa0 = sA + (wv * 32 + l16) * CH;
    const u16* pa1 = pa0 + 16 * CH;

#pragma unroll
    for (int kc = 0; kc < 4; ++kc) {
        int off = (((kc << 2) | quad) ^ l16) << 3;
        s16x8 a0 = *(const s16x8*)(pa0 + off);
        s16x8 a1 = *(const s16x8*)(pa1 + off);
#pragma unroll
        for (int t = 0; t < NT; ++t) {
            s16x8 bfr = *(const s16x8*)(sB + (t * 16 + l16) * CH + off);
            acc[0][t] = __builtin_amdgcn_mfma_f32_16x16x32_bf16(a0, bfr, acc[0][t], 0, 0, 0);
            acc[1][t] = __builtin_amdgcn_mfma_f32_16x16x32_bf16(a1, bfr, acc[1][t], 0, 0, 0);
        }
    }

#pragma unroll
    for (int t = 0; t < NT; ++t) {
        int col = t * 16 + l16;
        int bcol = col < ldc ? col : (ldc - 1);
        float bv = bias[bcol];
#pragma unroll
        for (int m = 0; m < 2; ++m) {
            int rbase = r0 + wv * 32 + m * 16 + quad * 4;
#pragma unroll
            for (int r = 0; r < 4; ++r) {
                int row = rbase + r;
                if (row < M && col < ldc) {
                    float v = acc[m][t][r] + bv;
                    if constexpr (RELU) v = fmaxf(v, 0.f);
                    Cp[(long)row * ldc + col] = v;
                }
            }
        }
    }
}

// ---------------------------------------------------------------------------
// BN stats stage 1: per-block per-channel sum/sumsq of f32 h -> pstats[blk][512]
// pstats[blk*512 + half*256 + c] = sum, [... + 128 + c] = sumsq. No atomics.
// ---------------------------------------------------------------------------
__global__ __launch_bounds__(256) void k_stats(const float* __restrict__ h,
                                               float* __restrict__ pstats, int M) {
    int c = threadIdx.x & 127;
    int half = threadIdx.x >> 7;
    int r = blockIdx.x * 256 + half;
    float s = 0.f, q = 0.f;
#pragma unroll 4
    for (int i = 0; i < 128; ++i) {
        if (r < M) {
            float v = h[(long)r * CH + c];
            s += v;
            q += v * v;
        }
        r += 2;
    }
    pstats[blockIdx.x * 512 + half * 256 + c] = s;
    pstats[blockIdx.x * 512 + half * 256 + 128 + c] = q;
}

// BN stats stage 2: scale[c]=g*rstd; shift[c]=b-mu*g*rstd. 1 block x 256.
__global__ __launch_bounds__(256) void k_bnparam(const float* __restrict__ pstats,
                                                 const float* __restrict__ g,
                                                 const float* __restrict__ b,
                                                 float* __restrict__ scale,
                                                 float* __restrict__ shift) {
    __shared__ float sm[256];
    int t = threadIdx.x;
    float acc = 0.f;
    for (int blk = 0; blk < NSB; ++blk)
        acc += pstats[blk * 512 + t] + pstats[blk * 512 + 256 + t];
    sm[t] = acc;
    __syncthreads();
    if (t < 128) {
        float mu = sm[t] / (float)NN;
        float var = sm[128 + t] / (float)NN - mu * mu;
        float rstd = rsqrtf(var + 1e-5f);
        float gg = g[t], bb = b[t];
        scale[t] = gg * rstd;
        shift[t] = bb - mu * gg * rstd;
    }
}

// ---------------------------------------------------------------------------
// global_add_pool, atomic-free: one block per graph; binary-search sorted batch
// for [start,end); direct write. grid 64 x 256.
// ---------------------------------------------------------------------------
__global__ __launch_bounds__(256) void k_pool(const float* __restrict__ x,
                                              const int* __restrict__ batch,
                                              float* __restrict__ pooled) {
    int g = blockIdx.x;
    int c = threadIdx.x & 127;
    int half = threadIdx.x >> 7;
    int lo = 0, hi = NN;
    while (lo < hi) { int mid = (lo + hi) >> 1; if (batch[mid] < g) lo = mid + 1; else hi = mid; }
    int start = lo;
    hi = NN;
    while (lo < hi) { int mid = (lo + hi) >> 1; if (batch[mid] < g + 1) lo = mid + 1; else hi = mid; }
    int end = lo;
    float s = 0.f;
    for (int r = start + half; r < end; r += 2)
        s += x[(long)r * CH + c];
    __shared__ float sm[256];
    sm[threadIdx.x] = s;
    __syncthreads();
    if (half == 0) pooled[g * CH + c] = sm[c] + sm[128 + c];
}

// out[b] = relu(pooled[b] @ W1 + b1) @ W2 + b2  ; grid 64 x 128, all f32
__global__ __launch_bounds__(128) void k_mlp(const float* __restrict__ pooled,
                                             const float* __restrict__ W1,
                                             const float* __restrict__ b1,
                                             const float* __restrict__ W2,
                                             const float* __restrict__ b2,
                                             float* __restrict__ out) {
    __shared__ float p[128], t1[128];
    int b = blockIdx.x, t = threadIdx.x;
    p[t] = pooled[b * CH + t];
    __syncthreads();
    float acc = b1[t];
    for (int k = 0; k < 128; ++k) acc += p[k] * W1[k * 128 + t];
    t1[t] = fmaxf(acc, 0.f);
    __syncthreads();
    if (t < 64) {
        float o = b2[t];
        for (int k = 0; k < 128; ++k) o += t1[k] * W2[k * 64 + t];
        out[b * 64 + t] = o;
    }
}

// ---------------------------------------------------------------------------
extern "C" void kernel_launch(void* const* d_in, const int* in_sizes, int n_in,
                              void* d_out, int out_size, void* d_ws, size_t ws_size,
                              hipStream_t stream) {
    const float* x_in   = (const float*)d_in[0];
    const int*   ei     = (const int*)d_in[1];
    const int*   batch  = (const int*)d_in[2];
    const float* convW1 = (const float*)d_in[3];
    const float* convb1 = (const float*)d_in[4];
    const float* bn_g   = (const float*)d_in[5];
    const float* bn_b   = (const float*)d_in[6];
    const float* convW2 = (const float*)d_in[7];
    const float* convb2 = (const float*)d_in[8];
    const float* recW1  = (const float*)d_in[9];
    const float* recb1  = (const float*)d_in[10];
    const float* recW2  = (const float*)d_in[11];
    const float* recb2  = (const float*)d_in[12];
    const float* recW3  = (const float*)d_in[13];
    const float* recb3  = (const float*)d_in[14];
    const float* mlpW1  = (const float*)d_in[15];
    const float* mlpb1  = (const float*)d_in[16];
    const float* mlpW2  = (const float*)d_in[17];
    const float* mlpb2  = (const float*)d_in[18];

    float* out   = (float*)d_out;      // [64*64] out, then [50000*4] x_rec
    float* x_rec = out + 4096;

    char* w = (char*)d_ws;
    float* y      = (float*)w;  w += (size_t)NN * CH * 4;    // x+agg -> h (in-place) -> rec scratch
    float* xc     = (float*)w;  w += (size_t)NN * CH * 4;    // layer output
    u16*   Wt     = (u16*)w;    w += (size_t)9 * 16384 * 2;  // transposed bf16 weights
    float* pstats = (float*)w;  w += (size_t)NSB * 512 * 4;  // BN partials
    float* scale  = (float*)w;  w += 128 * 4;
    float* shift  = (float*)w;  w += 128 * 4;
    float* pooled = (float*)w;  w += (size_t)BB * CH * 4;

    dim3 b256(256), b128(128);

    k_transpose_all<<<576, b256, 0, stream>>>(convW1, convW2, recW1, recW2, recW3, Wt);

    const float* cur = x_in;
    for (int l = 0; l < LL; ++l) {
        // y = cur  (then scatter-add neighbors into it)
        hipMemcpyAsync(y, cur, (size_t)NN * CH * 4, hipMemcpyDeviceToDevice, stream);
        k_scatter<<<2048, b256, 0, stream>>>(cur, ei, y);
        // GEMM1: h = (x+agg) @ W1 + b1, in-place over y
        k_gemm<8, false, false><<<391, b256, 0, stream>>>(
            y, Wt + l * 16384, convb1 + l * 128, nullptr, nullptr, y, NN, 128);
        k_stats<<<NSB, b256, 0, stream>>>(y, pstats, NN);
        k_bnparam<<<1, b256, 0, stream>>>(pstats, bn_g + l * 128, bn_b + l * 128, scale, shift);
        // GEMM2: xc = relu(relu(BN(h)) @ W2 + b2), BN fused into A staging
        k_gemm<8, true, true><<<391, b256, 0, stream>>>(
            y, Wt + (3 + l) * 16384, convb2 + l * 128, scale, shift, xc, NN, 128);
        cur = xc;
    }
    // reconstruction head (f32 I/O; rec2 in-place over y)
    k_gemm<8, false, true><<<391, b256, 0, stream>>>(
        xc, Wt + 6 * 16384, recb1, nullptr, nullptr, y, NN, 128);
    k_gemm<8, false, true><<<391, b256, 0, stream>>>(
        y, Wt + 7 * 16384, recb2, nullptr, nullptr, y, NN, 128);
    k_gemm<1, false, true><<<391, b256, 0, stream>>>(
        y, Wt + 8 * 16384, recb3, nullptr, nullptr, x_rec, NN, 4);
    // pooling + final MLP (atomic-free)
    k_pool<<<64, b256, 0, stream>>>(xc, batch, pooled);
    k_mlp<<<64, b128, 0, stream>>>(pooled, mlpW1, mlpb1, mlpW2, mlpb2, out);
}

// Round 4
// 713.829 us; speedup vs baseline: 2.7932x; 2.7932x over previous
//
#include <hip/hip_runtime.h>

#define NN 50000
#define EE 600000
#define BB 64
#define CH 128
#define LL 3
#define NGB 391   // GEMM row-blocks = ceil(50000/128), also stats partials

typedef unsigned short u16;
typedef unsigned int u32;
typedef short s16x8 __attribute__((ext_vector_type(8)));
typedef float f32x4 __attribute__((ext_vector_type(4)));

__device__ __forceinline__ u16 f2b(float f) {
    u32 x = __float_as_uint(f);
    return (u16)((x + 0x7FFFu + ((x >> 16) & 1u)) >> 16);  // RNE f32->bf16
}

// ---------------------------------------------------------------------------
// CSR build (edge_index is fixed -> build by dst once per call, ~25 us)
// ---------------------------------------------------------------------------
__global__ __launch_bounds__(256) void k_zero(int* __restrict__ p, int n) {
    int i = blockIdx.x * 256 + threadIdx.x;
    if (i < n) p[i] = 0;
}

__global__ __launch_bounds__(256) void k_count(const int* __restrict__ ei,
                                               int* __restrict__ deg) {
    int e = blockIdx.x * 256 + threadIdx.x;
    if (e < EE) atomicAdd(&deg[ei[EE + e]], 1);
}

// 1 block x 256: per-thread chunk sums -> Hillis-Steele scan -> rowptr & cur
__global__ __launch_bounds__(256) void k_scan(const int* __restrict__ deg,
                                              int* __restrict__ rowptr,
                                              int* __restrict__ cur) {
    __shared__ int ps[256];
    const int CHK = 196;  // 256*196 >= 50000
    int t = threadIdx.x;
    int lo = t * CHK, hi = min(lo + CHK, NN);
    int s = 0;
    for (int i = lo; i < hi; ++i) s += deg[i];
    ps[t] = s;
    __syncthreads();
    for (int off = 1; off < 256; off <<= 1) {
        int u = (t >= off) ? ps[t - off] : 0;
        __syncthreads();
        ps[t] += u;
        __syncthreads();
    }
    int run = ps[t] - s;  // exclusive prefix
    for (int i = lo; i < hi; ++i) {
        rowptr[i] = run;
        cur[i] = run;
        run += deg[i];
    }
    if (t == 255) rowptr[NN] = run;
}

__global__ __launch_bounds__(256) void k_fill(const int* __restrict__ ei,
                                              int* __restrict__ cur,
                                              int* __restrict__ perm) {
    int e = blockIdx.x * 256 + threadIdx.x;
    if (e < EE) {
        int dst = ei[EE + e];
        int idx = atomicAdd(&cur[dst], 1);
        perm[idx] = ei[e];
    }
}

// ---------------------------------------------------------------------------
// Atomic-free aggregation: one wave per dst node.
// y[dst] = x[dst] + sum_{src in CSR[dst]} x[src]   (lane handles 2 channels)
// ---------------------------------------------------------------------------
__global__ __launch_bounds__(256) void k_gather(const float* __restrict__ x,
                                                const int* __restrict__ rowptr,
                                                const int* __restrict__ perm,
                                                float* __restrict__ y) {
    int dst = __builtin_amdgcn_readfirstlane(blockIdx.x * 4 + (threadIdx.x >> 6));
    int lane = threadIdx.x & 63;
    if (dst >= NN) return;
    int beg = rowptr[dst], end = rowptr[dst + 1];
    int co = lane * 2;
    float2 acc = *(const float2*)(x + (long)dst * CH + co);
    for (int j = beg; j < end; ++j) {
        int src = perm[j];  // wave-uniform -> scalar load
        float2 v = *(const float2*)(x + (long)src * CH + co);
        acc.x += v.x;
        acc.y += v.y;
    }
    *(float2*)(y + (long)dst * CH + co) = acc;
}

// ---------------------------------------------------------------------------
// Transpose + convert weights once: Wt[slot][n*128+k] = bf16(W[k][n])
// slots 0-2: convW1[l], 3-5: convW2[l], 6: recW1, 7: recW2, 8: recW3 (zero-pad)
// ---------------------------------------------------------------------------
__global__ __launch_bounds__(256) void k_transpose_all(
    const float* __restrict__ cW1, const float* __restrict__ cW2,
    const float* __restrict__ rW1, const float* __restrict__ rW2,
    const float* __restrict__ rW3, u16* __restrict__ Wt) {
    int idx = blockIdx.x * 256 + threadIdx.x;
    if (idx < 8 * 16384) {
        int slot = idx >> 14;
        int wi = idx & 16383;
        int k = wi >> 7, n = wi & 127;
        const float* src = slot < 3 ? cW1 + slot * 16384
                         : slot < 6 ? cW2 + (slot - 3) * 16384
                         : slot == 6 ? rW1 : rW2;
        Wt[slot * 16384 + n * 128 + k] = f2b(src[wi]);
    } else if (idx < 9 * 16384) {
        int j = idx - 8 * 16384;
        int n = j >> 7, k = j & 127;
        Wt[8 * 16384 + j] = (n < 4) ? f2b(rW3[k * 4 + n]) : (u16)0;
    }
}

// ---------------------------------------------------------------------------
// MFMA GEMM: C[M x ldc] = op(A)[M x 128] @ Wt^T + bias, K = 128, f32 I/O.
// BN: relu(scale*a+shift) fused into A staging.  RELU: relu on output.
// STATS: fused per-block per-channel sum/sumsq of C (pre-relu) -> pstats[blk].
// LDS XOR-swizzle (chunk c of row r at chunk c^(r&15)); layouts verified
// m89/m91: A-frag A[m=lane&15][k=quad*8+j]; C/D col=lane&15,row=quad*4+reg.
// In-place safe (block stages all A rows before writing C).
// ---------------------------------------------------------------------------
template <int NT, bool BN, bool RELU, bool STATS>
__global__ __launch_bounds__(256) void k_gemm(
    const float* __restrict__ Ap, const u16* __restrict__ Wt,
    const float* __restrict__ bias, const float* __restrict__ scale,
    const float* __restrict__ shift, float* __restrict__ Cp,
    float* __restrict__ pstats, int M, int ldc) {
    __shared__ u16 sA[128 * CH];
    __shared__ u16 sB[NT * 16 * CH];
    const int tid = threadIdx.x;
    const int s = tid & 15;
    const int rr = tid >> 4;
    const int r0 = blockIdx.x * 128;

    float sc[8], sh[8];
    if constexpr (BN) {
#pragma unroll
        for (int j = 0; j < 8; ++j) {
            sc[j] = scale[8 * s + j];
            sh[j] = shift[8 * s + j];
        }
    }

#pragma unroll
    for (int it = 0; it < NT; ++it) {
        int n = it * 16 + rr;
        uint4 u = *(const uint4*)(Wt + n * CH + 8 * s);
        int phys = (s ^ (n & 15)) * 8;
        *(uint4*)(&sB[n * CH + phys]) = u;
    }
#pragma unroll
    for (int it = 0; it < 8; ++it) {
        int lr = it * 16 + rr;
        int gr = r0 + lr;
        union { u16 pk[8]; uint4 v; } uu;
        if (gr < M) {
            const float* Af = Ap + (long)gr * CH + 8 * s;
            float4 f0 = *(const float4*)Af;
            float4 f1 = *(const float4*)(Af + 4);
            float vj[8] = {f0.x, f0.y, f0.z, f0.w, f1.x, f1.y, f1.z, f1.w};
#pragma unroll
            for (int j = 0; j < 8; ++j) {
                float v = vj[j];
                if constexpr (BN) v = fmaxf(v * sc[j] + sh[j], 0.f);
                uu.pk[j] = f2b(v);
            }
        } else {
#pragma unroll
            for (int j = 0; j < 8; ++j) uu.pk[j] = 0;
        }
        int phys = (s ^ (lr & 15)) * 8;
        *(uint4*)(&sA[lr * CH + phys]) = uu.v;
    }
    __syncthreads();

    const int lane = tid & 63;
    const int wv = tid >> 6;
    const int quad = lane >> 4;
    const int l16 = lane & 15;

    f32x4 zero4 = {0.f, 0.f, 0.f, 0.f};
    f32x4 acc[2][NT];
#pragma unroll
    for (int m = 0; m < 2; ++m)
#pragma unroll
        for (int t = 0; t < NT; ++t) acc[m][t] = zero4;

    const u16* pa0 = sA + (wv * 32 + l16) * CH;
    const u16* pa1 = pa0 + 16 * CH;

#pragma unroll
    for (int kc = 0; kc < 4; ++kc) {
        int off = (((kc << 2) | quad) ^ l16) << 3;
        s16x8 a0 = *(const s16x8*)(pa0 + off);
        s16x8 a1 = *(const s16x8*)(pa1 + off);
#pragma unroll
        for (int t = 0; t < NT; ++t) {
            s16x8 bfr = *(const s16x8*)(sB + (t * 16 + l16) * CH + off);
            acc[0][t] = __builtin_amdgcn_mfma_f32_16x16x32_bf16(a0, bfr, acc[0][t], 0, 0, 0);
            acc[1][t] = __builtin_amdgcn_mfma_f32_16x16x32_bf16(a1, bfr, acc[1][t], 0, 0, 0);
        }
    }

    float ss[NT], qq[NT];
    if constexpr (STATS) {
#pragma unroll
        for (int t = 0; t < NT; ++t) { ss[t] = 0.f; qq[t] = 0.f; }
    }

#pragma unroll
    for (int t = 0; t < NT; ++t) {
        int col = t * 16 + l16;
        int bcol = col < ldc ? col : (ldc - 1);
        float bv = bias[bcol];
#pragma unroll
        for (int m = 0; m < 2; ++m) {
            int rbase = r0 + wv * 32 + m * 16 + quad * 4;
#pragma unroll
            for (int r = 0; r < 4; ++r) {
                int row = rbase + r;
                if (row < M && col < ldc) {
                    float v = acc[m][t][r] + bv;
                    if constexpr (STATS) { ss[t] += v; qq[t] += v * v; }
                    if constexpr (RELU) v = fmaxf(v, 0.f);
                    Cp[(long)row * ldc + col] = v;
                }
            }
        }
    }

    if constexpr (STATS) {
        // quad butterfly: sum the 4 quad-groups (each lane ends with wave sum)
#pragma unroll
        for (int t = 0; t < NT; ++t) {
            ss[t] += __shfl_xor(ss[t], 16);
            ss[t] += __shfl_xor(ss[t], 32);
            qq[t] += __shfl_xor(qq[t], 16);
            qq[t] += __shfl_xor(qq[t], 32);
        }
        float* red = (float*)sA;  // alias: 4 waves x 256 floats = 4 KB
        __syncthreads();          // all waves done reading sA
        if (lane < 16) {
#pragma unroll
            for (int t = 0; t < NT; ++t) {
                red[wv * 256 + t * 16 + l16] = ss[t];
                red[wv * 256 + 128 + t * 16 + l16] = qq[t];
            }
        }
        __syncthreads();
        // 256 threads: c<128 -> sum, c>=128 -> sumsq
        float v = red[tid] + red[256 + tid] + red[512 + tid] + red[768 + tid];
        pstats[(long)blockIdx.x * 256 + tid] = v;
    }
}

// BN param: reduce pstats over NGB blocks. scale=g*rstd; shift=b-mu*g*rstd.
__global__ __launch_bounds__(256) void k_bnparam(const float* __restrict__ pstats,
                                                 const float* __restrict__ g,
                                                 const float* __restrict__ b,
                                                 float* __restrict__ scale,
                                                 float* __restrict__ shift) {
    __shared__ float sm[256];
    int t = threadIdx.x;
    float acc = 0.f;
    for (int blk = 0; blk < NGB; ++blk) acc += pstats[blk * 256 + t];
    sm[t] = acc;
    __syncthreads();
    if (t < 128) {
        float mu = sm[t] / (float)NN;
        float var = sm[128 + t] / (float)NN - mu * mu;
        float rstd = rsqrtf(var + 1e-5f);
        float gg = g[t], bb = b[t];
        scale[t] = gg * rstd;
        shift[t] = bb - mu * gg * rstd;
    }
}

// ---------------------------------------------------------------------------
// global_add_pool, atomic-free: one block per graph; binary-search sorted batch.
// ---------------------------------------------------------------------------
__global__ __launch_bounds__(256) void k_pool(const float* __restrict__ x,
                                              const int* __restrict__ batch,
                                              float* __restrict__ pooled) {
    int g = blockIdx.x;
    int c = threadIdx.x & 127;
    int half = threadIdx.x >> 7;
    int lo = 0, hi = NN;
    while (lo < hi) { int mid = (lo + hi) >> 1; if (batch[mid] < g) lo = mid + 1; else hi = mid; }
    int start = lo;
    hi = NN;
    while (lo < hi) { int mid = (lo + hi) >> 1; if (batch[mid] < g + 1) lo = mid + 1; else hi = mid; }
    int end = lo;
    float s = 0.f;
    for (int r = start + half; r < end; r += 2)
        s += x[(long)r * CH + c];
    __shared__ float sm[256];
    sm[threadIdx.x] = s;
    __syncthreads();
    if (half == 0) pooled[g * CH + c] = sm[c] + sm[128 + c];
}

// out[b] = relu(pooled[b] @ W1 + b1) @ W2 + b2  ; grid 64 x 128, all f32
__global__ __launch_bounds__(128) void k_mlp(const float* __restrict__ pooled,
                                             const float* __restrict__ W1,
                                             const float* __restrict__ b1,
                                             const float* __restrict__ W2,
                                             const float* __restrict__ b2,
                                             float* __restrict__ out) {
    __shared__ float p[128], t1[128];
    int b = blockIdx.x, t = threadIdx.x;
    p[t] = pooled[b * CH + t];
    __syncthreads();
    float acc = b1[t];
    for (int k = 0; k < 128; ++k) acc += p[k] * W1[k * 128 + t];
    t1[t] = fmaxf(acc, 0.f);
    __syncthreads();
    if (t < 64) {
        float o = b2[t];
        for (int k = 0; k < 128; ++k) o += t1[k] * W2[k * 64 + t];
        out[b * 64 + t] = o;
    }
}

// ---------------------------------------------------------------------------
extern "C" void kernel_launch(void* const* d_in, const int* in_sizes, int n_in,
                              void* d_out, int out_size, void* d_ws, size_t ws_size,
                              hipStream_t stream) {
    const float* x_in   = (const float*)d_in[0];
    const int*   ei     = (const int*)d_in[1];
    const int*   batch  = (const int*)d_in[2];
    const float* convW1 = (const float*)d_in[3];
    const float* convb1 = (const float*)d_in[4];
    const float* bn_g   = (const float*)d_in[5];
    const float* bn_b   = (const float*)d_in[6];
    const float* convW2 = (const float*)d_in[7];
    const float* convb2 = (const float*)d_in[8];
    const float* recW1  = (const float*)d_in[9];
    const float* recb1  = (const float*)d_in[10];
    const float* recW2  = (const float*)d_in[11];
    const float* recb2  = (const float*)d_in[12];
    const float* recW3  = (const float*)d_in[13];
    const float* recb3  = (const float*)d_in[14];
    const float* mlpW1  = (const float*)d_in[15];
    const float* mlpb1  = (const float*)d_in[16];
    const float* mlpW2  = (const float*)d_in[17];
    const float* mlpb2  = (const float*)d_in[18];

    float* out   = (float*)d_out;      // [64*64] out, then [50000*4] x_rec
    float* x_rec = out + 4096;

    char* w = (char*)d_ws;
    float* y      = (float*)w;  w += (size_t)NN * CH * 4;      // x+agg -> h (in-place) -> rec scratch
    float* xc     = (float*)w;  w += (size_t)NN * CH * 4;      // layer output
    u16*   Wt     = (u16*)w;    w += (size_t)9 * 16384 * 2;    // transposed bf16 weights
    float* pstats = (float*)w;  w += (size_t)NGB * 256 * 4;    // fused BN partials
    float* scale  = (float*)w;  w += 128 * 4;
    float* shift  = (float*)w;  w += 128 * 4;
    float* pooled = (float*)w;  w += (size_t)BB * CH * 4;
    int*   deg    = (int*)w;    w += (size_t)NN * 4;
    int*   rowptr = (int*)w;    w += (size_t)(NN + 1) * 4;
    int*   cur    = (int*)w;    w += (size_t)NN * 4;
    int*   perm   = (int*)w;    w += (size_t)EE * 4;

    dim3 b256(256), b128(128);

    // CSR build (once per call)
    k_zero<<<196, b256, 0, stream>>>(deg, NN);
    k_count<<<2344, b256, 0, stream>>>(ei, deg);
    k_scan<<<1, b256, 0, stream>>>(deg, rowptr, cur);
    k_fill<<<2344, b256, 0, stream>>>(ei, cur, perm);
    k_transpose_all<<<576, b256, 0, stream>>>(convW1, convW2, recW1, recW2, recW3, Wt);

    const float* cur_x = x_in;
    for (int l = 0; l < LL; ++l) {
        // y = x + neighbor sum (atomic-free gather)
        k_gather<<<12500, b256, 0, stream>>>(cur_x, rowptr, perm, y);
        // GEMM1: h = y @ W1 + b1 in-place, fused BN-stats partials
        k_gemm<8, false, false, true><<<NGB, b256, 0, stream>>>(
            y, Wt + l * 16384, convb1 + l * 128, nullptr, nullptr, y, pstats, NN, 128);
        k_bnparam<<<1, b256, 0, stream>>>(pstats, bn_g + l * 128, bn_b + l * 128, scale, shift);
        // GEMM2: xc = relu(relu(BN(h)) @ W2 + b2), BN fused into A staging
        k_gemm<8, true, true, false><<<NGB, b256, 0, stream>>>(
            y, Wt + (3 + l) * 16384, convb2 + l * 128, scale, shift, xc, nullptr, NN, 128);
        cur_x = xc;
    }
    // reconstruction head (rec2 in-place over y)
    k_gemm<8, false, true, false><<<NGB, b256, 0, stream>>>(
        xc, Wt + 6 * 16384, recb1, nullptr, nullptr, y, nullptr, NN, 128);
    k_gemm<8, false, true, false><<<NGB, b256, 0, stream>>>(
        y, Wt + 7 * 16384, recb2, nullptr, nullptr, y, nullptr, NN, 128);
    k_gemm<1, false, true, false><<<NGB, b256, 0, stream>>>(
        y, Wt + 8 * 16384, recb3, nullptr, nullptr, x_rec, nullptr, NN, 4);
    // pooling + final MLP (atomic-free)
    k_pool<<<64, b256, 0, stream>>>(xc, batch, pooled);
    k_mlp<<<64, b128, 0, stream>>>(pooled, mlpW1, mlpb1, mlpW2, mlpb2, out);
}

// Round 5
// 588.615 us; speedup vs baseline: 3.3874x; 1.2127x over previous
//
#include <hip/hip_runtime.h>

#define NN 50000
#define EE 600000
#define BB 64
#define CH 128
#define LL 3
#define NGB 391   // GEMM row-blocks = ceil(50000/128), also stats partials
#define NSB 196   // scan blocks = ceil(50000/256)

typedef unsigned short u16;
typedef unsigned int u32;
typedef short s16x8 __attribute__((ext_vector_type(8)));
typedef float f32x4 __attribute__((ext_vector_type(4)));

__device__ __forceinline__ u16 f2b(float f) {
    u32 x = __float_as_uint(f);
    return (u16)((x + 0x7FFFu + ((x >> 16) & 1u)) >> 16);  // RNE f32->bf16
}
__device__ __forceinline__ float b2f(u16 u) {
    return __uint_as_float(((u32)u) << 16);
}

// ---------------------------------------------------------------------------
// CSR build (edge_index fixed -> rebuild per call; ws is re-poisoned)
// ---------------------------------------------------------------------------
__global__ __launch_bounds__(256) void k_zero(int* __restrict__ p, int n) {
    int i = blockIdx.x * 256 + threadIdx.x;
    if (i < n) p[i] = 0;
}

__global__ __launch_bounds__(256) void k_count(const int* __restrict__ ei,
                                               int* __restrict__ deg) {
    int e = blockIdx.x * 256 + threadIdx.x;
    if (e < EE) atomicAdd(&deg[ei[EE + e]], 1);
}

// stage A: per-block (256 elems) sum of deg -> bsum[blk]
__global__ __launch_bounds__(256) void k_scanA(const int* __restrict__ deg,
                                               int* __restrict__ bsum) {
    __shared__ int sm[256];
    int i = blockIdx.x * 256 + threadIdx.x;
    sm[threadIdx.x] = (i < NN) ? deg[i] : 0;
    __syncthreads();
    for (int off = 128; off > 0; off >>= 1) {
        if (threadIdx.x < off) sm[threadIdx.x] += sm[threadIdx.x + off];
        __syncthreads();
    }
    if (threadIdx.x == 0) bsum[blockIdx.x] = sm[0];
}

// stage B: scan bsum (196) in LDS -> block offset; local scan of 256 deg ->
// rowptr & cur (exclusive); last element writes rowptr[NN].
__global__ __launch_bounds__(256) void k_scanB(const int* __restrict__ deg,
                                               const int* __restrict__ bsum,
                                               int* __restrict__ rowptr,
                                               int* __restrict__ cur) {
    __shared__ int sb[256], sd[256];
    int t = threadIdx.x;
    sb[t] = (t < NSB) ? bsum[t] : 0;
    __syncthreads();
    for (int off = 1; off < 256; off <<= 1) {
        int v = (t >= off) ? sb[t - off] : 0;
        __syncthreads();
        sb[t] += v;
        __syncthreads();
    }
    int blockOff = (blockIdx.x == 0) ? 0 : sb[blockIdx.x - 1];
    int i = blockIdx.x * 256 + t;
    int d = (i < NN) ? deg[i] : 0;
    sd[t] = d;
    __syncthreads();
    for (int off = 1; off < 256; off <<= 1) {
        int v = (t >= off) ? sd[t - off] : 0;
        __syncthreads();
        sd[t] += v;
        __syncthreads();
    }
    int excl = blockOff + sd[t] - d;
    if (i < NN) { rowptr[i] = excl; cur[i] = excl; }
    if (i == NN - 1) rowptr[NN] = excl + d;
}

__global__ __launch_bounds__(256) void k_fill(const int* __restrict__ ei,
                                              int* __restrict__ cur,
                                              int* __restrict__ perm) {
    int e = blockIdx.x * 256 + threadIdx.x;
    if (e < EE) {
        int dst = ei[EE + e];
        int idx = atomicAdd(&cur[dst], 1);
        perm[idx] = ei[e];
    }
}

// ---------------------------------------------------------------------------
// Gather, layer 1: y16[dst] = bf16( x[dst] + sum x[src] ), x f32.
// One wave per dst; 64 perm entries vector-loaded then shfl-broadcast.
// ---------------------------------------------------------------------------
__global__ __launch_bounds__(256) void k_gather1(const float* __restrict__ x,
                                                 const int* __restrict__ rowptr,
                                                 const int* __restrict__ perm,
                                                 u16* __restrict__ y) {
    int dst = blockIdx.x * 4 + (threadIdx.x >> 6);
    if (dst >= NN) return;
    int lane = threadIdx.x & 63;
    int beg = rowptr[dst], end = rowptr[dst + 1];
    int co = lane * 2;
    float2 a = *(const float2*)(x + (long)dst * CH + co);
    for (int j = beg; j < end; j += 64) {
        int pidx = (j + lane < end) ? perm[j + lane] : 0;
        int cnt = min(64, end - j);
        for (int q = 0; q < cnt; ++q) {
            int src = __shfl(pidx, q);
            float2 v = *(const float2*)(x + (long)src * CH + co);
            a.x += v.x;
            a.y += v.y;
        }
    }
    u32 pk = ((u32)f2b(a.y) << 16) | (u32)f2b(a.x);
    *(u32*)(y + (long)dst * CH + co) = pk;
}

// Gather, layers 2-3: bf16 in, bf16 out (accumulate f32).
__global__ __launch_bounds__(256) void k_gatherB(const u16* __restrict__ x,
                                                 const int* __restrict__ rowptr,
                                                 const int* __restrict__ perm,
                                                 u16* __restrict__ y) {
    int dst = blockIdx.x * 4 + (threadIdx.x >> 6);
    if (dst >= NN) return;
    int lane = threadIdx.x & 63;
    int beg = rowptr[dst], end = rowptr[dst + 1];
    int co = lane * 2;
    u32 u0 = *(const u32*)(x + (long)dst * CH + co);
    float2 a = {b2f((u16)(u0 & 0xffff)), b2f((u16)(u0 >> 16))};
    for (int j = beg; j < end; j += 64) {
        int pidx = (j + lane < end) ? perm[j + lane] : 0;
        int cnt = min(64, end - j);
        for (int q = 0; q < cnt; ++q) {
            int src = __shfl(pidx, q);
            u32 uv = *(const u32*)(x + (long)src * CH + co);
            a.x += b2f((u16)(uv & 0xffff));
            a.y += b2f((u16)(uv >> 16));
        }
    }
    u32 pk = ((u32)f2b(a.y) << 16) | (u32)f2b(a.x);
    *(u32*)(y + (long)dst * CH + co) = pk;
}

// ---------------------------------------------------------------------------
// Transpose + convert weights once: Wt[slot][n*128+k] = bf16(W[k][n])
// slots 0-2: convW1[l], 3-5: convW2[l], 6: recW1, 7: recW2, 8: recW3 (zero-pad)
// ---------------------------------------------------------------------------
__global__ __launch_bounds__(256) void k_transpose_all(
    const float* __restrict__ cW1, const float* __restrict__ cW2,
    const float* __restrict__ rW1, const float* __restrict__ rW2,
    const float* __restrict__ rW3, u16* __restrict__ Wt) {
    int idx = blockIdx.x * 256 + threadIdx.x;
    if (idx < 8 * 16384) {
        int slot = idx >> 14;
        int wi = idx & 16383;
        int k = wi >> 7, n = wi & 127;
        const float* src = slot < 3 ? cW1 + slot * 16384
                         : slot < 6 ? cW2 + (slot - 3) * 16384
                         : slot == 6 ? rW1 : rW2;
        Wt[slot * 16384 + n * 128 + k] = f2b(src[wi]);
    } else if (idx < 9 * 16384) {
        int j = idx - 8 * 16384;
        int n = j >> 7, k = j & 127;
        Wt[8 * 16384 + j] = (n < 4) ? f2b(rW3[k * 4 + n]) : (u16)0;
    }
}

// ---------------------------------------------------------------------------
// MFMA GEMM: C[M x ldc] = op(A)[M x 128] @ Wt^T + bias, K = 128.
// ABF16: A stored bf16 (direct stage). BN (f32 A only): relu(scale*a+shift).
// RELU: relu on output. STATS: fused per-block sum/sumsq of C (pre-relu).
// OUTBF16: C stored bf16.  LDS XOR-swizzle chunk c^(r&15); layouts m89/m91.
// In-place safe (block stages all A rows before writing C).
// ---------------------------------------------------------------------------
template <int NT, bool ABF16, bool BN, bool RELU, bool STATS, bool OUTBF16>
__global__ __launch_bounds__(256) void k_gemm(
    const void* __restrict__ Ap, const u16* __restrict__ Wt,
    const float* __restrict__ bias, const float* __restrict__ scale,
    const float* __restrict__ shift, void* __restrict__ Cp,
    float* __restrict__ pstats, int M, int ldc) {
    __shared__ u16 sA[128 * CH];
    __shared__ u16 sB[NT * 16 * CH];
    const int tid = threadIdx.x;
    const int s = tid & 15;
    const int rr = tid >> 4;
    const int r0 = blockIdx.x * 128;

    float sc[8], sh[8];
    if constexpr (BN) {
#pragma unroll
        for (int j = 0; j < 8; ++j) {
            sc[j] = scale[8 * s + j];
            sh[j] = shift[8 * s + j];
        }
    }

#pragma unroll
    for (int it = 0; it < NT; ++it) {
        int n = it * 16 + rr;
        uint4 u = *(const uint4*)(Wt + n * CH + 8 * s);
        int phys = (s ^ (n & 15)) * 8;
        *(uint4*)(&sB[n * CH + phys]) = u;
    }
#pragma unroll
    for (int it = 0; it < 8; ++it) {
        int lr = it * 16 + rr;
        int gr = r0 + lr;
        union { u16 pk[8]; uint4 v; } uu;
        if (gr < M) {
            if constexpr (ABF16) {
                uu.v = *(const uint4*)((const u16*)Ap + (long)gr * CH + 8 * s);
            } else {
                const float* Af = (const float*)Ap + (long)gr * CH + 8 * s;
                float4 f0 = *(const float4*)Af;
                float4 f1 = *(const float4*)(Af + 4);
                float vj[8] = {f0.x, f0.y, f0.z, f0.w, f1.x, f1.y, f1.z, f1.w};
#pragma unroll
                for (int j = 0; j < 8; ++j) {
                    float v = vj[j];
                    if constexpr (BN) v = fmaxf(v * sc[j] + sh[j], 0.f);
                    uu.pk[j] = f2b(v);
                }
            }
        } else {
#pragma unroll
            for (int j = 0; j < 8; ++j) uu.pk[j] = 0;
        }
        int phys = (s ^ (lr & 15)) * 8;
        *(uint4*)(&sA[lr * CH + phys]) = uu.v;
    }
    __syncthreads();

    const int lane = tid & 63;
    const int wv = tid >> 6;
    const int quad = lane >> 4;
    const int l16 = lane & 15;

    f32x4 zero4 = {0.f, 0.f, 0.f, 0.f};
    f32x4 acc[2][NT];
#pragma unroll
    for (int m = 0; m < 2; ++m)
#pragma unroll
        for (int t = 0; t < NT; ++t) acc[m][t] = zero4;

    const u16* pa0 = sA + (wv * 32 + l16) * CH;
    const u16* pa1 = pa0 + 16 * CH;

#pragma unroll
    for (int kc = 0; kc < 4; ++kc) {
        int off = (((kc << 2) | quad) ^ l16) << 3;
        s16x8 a0 = *(const s16x8*)(pa0 + off);
        s16x8 a1 = *(const s16x8*)(pa1 + off);
#pragma unroll
        for (int t = 0; t < NT; ++t) {
            s16x8 bfr = *(const s16x8*)(sB + (t * 16 + l16) * CH + off);
            acc[0][t] = __builtin_amdgcn_mfma_f32_16x16x32_bf16(a0, bfr, acc[0][t], 0, 0, 0);
            acc[1][t] = __builtin_amdgcn_mfma_f32_16x16x32_bf16(a1, bfr, acc[1][t], 0, 0, 0);
        }
    }

    float ss[NT], qq[NT];
    if constexpr (STATS) {
#pragma unroll
        for (int t = 0; t < NT; ++t) { ss[t] = 0.f; qq[t] = 0.f; }
    }

#pragma unroll
    for (int t = 0; t < NT; ++t) {
        int col = t * 16 + l16;
        int bcol = col < ldc ? col : (ldc - 1);
        float bv = bias[bcol];
#pragma unroll
        for (int m = 0; m < 2; ++m) {
            int rbase = r0 + wv * 32 + m * 16 + quad * 4;
#pragma unroll
            for (int r = 0; r < 4; ++r) {
                int row = rbase + r;
                if (row < M && col < ldc) {
                    float v = acc[m][t][r] + bv;
                    if constexpr (STATS) { ss[t] += v; qq[t] += v * v; }
                    if constexpr (RELU) v = fmaxf(v, 0.f);
                    if constexpr (OUTBF16)
                        ((u16*)Cp)[(long)row * ldc + col] = f2b(v);
                    else
                        ((float*)Cp)[(long)row * ldc + col] = v;
                }
            }
        }
    }

    if constexpr (STATS) {
#pragma unroll
        for (int t = 0; t < NT; ++t) {
            ss[t] += __shfl_xor(ss[t], 16);
            ss[t] += __shfl_xor(ss[t], 32);
            qq[t] += __shfl_xor(qq[t], 16);
            qq[t] += __shfl_xor(qq[t], 32);
        }
        float* red = (float*)sA;
        __syncthreads();
        if (lane < 16) {
#pragma unroll
            for (int t = 0; t < NT; ++t) {
                red[wv * 256 + t * 16 + l16] = ss[t];
                red[wv * 256 + 128 + t * 16 + l16] = qq[t];
            }
        }
        __syncthreads();
        float v = red[tid] + red[256 + tid] + red[512 + tid] + red[768 + tid];
        pstats[(long)blockIdx.x * 256 + tid] = v;
    }
}

// BN param: reduce pstats over NGB blocks. scale=g*rstd; shift=b-mu*g*rstd.
__global__ __launch_bounds__(256) void k_bnparam(const float* __restrict__ pstats,
                                                 const float* __restrict__ g,
                                                 const float* __restrict__ b,
                                                 float* __restrict__ scale,
                                                 float* __restrict__ shift) {
    __shared__ float sm[256];
    int t = threadIdx.x;
    float acc = 0.f;
    for (int blk = 0; blk < NGB; ++blk) acc += pstats[blk * 256 + t];
    sm[t] = acc;
    __syncthreads();
    if (t < 128) {
        float mu = sm[t] / (float)NN;
        float var = sm[128 + t] / (float)NN - mu * mu;
        float rstd = rsqrtf(var + 1e-5f);
        float gg = g[t], bb = b[t];
        scale[t] = gg * rstd;
        shift[t] = bb - mu * gg * rstd;
    }
}

// ---------------------------------------------------------------------------
// global_add_pool (bf16 in), atomic-free: one block per graph; binary search.
// ---------------------------------------------------------------------------
__global__ __launch_bounds__(256) void k_pool(const u16* __restrict__ x,
                                              const int* __restrict__ batch,
                                              float* __restrict__ pooled) {
    int g = blockIdx.x;
    int c = threadIdx.x & 127;
    int half = threadIdx.x >> 7;
    int lo = 0, hi = NN;
    while (lo < hi) { int mid = (lo + hi) >> 1; if (batch[mid] < g) lo = mid + 1; else hi = mid; }
    int start = lo;
    hi = NN;
    while (lo < hi) { int mid = (lo + hi) >> 1; if (batch[mid] < g + 1) lo = mid + 1; else hi = mid; }
    int end = lo;
    float s = 0.f;
    for (int r = start + half; r < end; r += 2)
        s += b2f(x[(long)r * CH + c]);
    __shared__ float sm[256];
    sm[threadIdx.x] = s;
    __syncthreads();
    if (half == 0) pooled[g * CH + c] = sm[c] + sm[128 + c];
}

// out[b] = relu(pooled[b] @ W1 + b1) @ W2 + b2  ; grid 64 x 128, all f32
__global__ __launch_bounds__(128) void k_mlp(const float* __restrict__ pooled,
                                             const float* __restrict__ W1,
                                             const float* __restrict__ b1,
                                             const float* __restrict__ W2,
                                             const float* __restrict__ b2,
                                             float* __restrict__ out) {
    __shared__ float p[128], t1[128];
    int b = blockIdx.x, t = threadIdx.x;
    p[t] = pooled[b * CH + t];
    __syncthreads();
    float acc = b1[t];
    for (int k = 0; k < 128; ++k) acc += p[k] * W1[k * 128 + t];
    t1[t] = fmaxf(acc, 0.f);
    __syncthreads();
    if (t < 64) {
        float o = b2[t];
        for (int k = 0; k < 128; ++k) o += t1[k] * W2[k * 64 + t];
        out[b * 64 + t] = o;
    }
}

// ---------------------------------------------------------------------------
extern "C" void kernel_launch(void* const* d_in, const int* in_sizes, int n_in,
                              void* d_out, int out_size, void* d_ws, size_t ws_size,
                              hipStream_t stream) {
    const float* x_in   = (const float*)d_in[0];
    const int*   ei     = (const int*)d_in[1];
    const int*   batch  = (const int*)d_in[2];
    const float* convW1 = (const float*)d_in[3];
    const float* convb1 = (const float*)d_in[4];
    const float* bn_g   = (const float*)d_in[5];
    const float* bn_b   = (const float*)d_in[6];
    const float* convW2 = (const float*)d_in[7];
    const float* convb2 = (const float*)d_in[8];
    const float* recW1  = (const float*)d_in[9];
    const float* recb1  = (const float*)d_in[10];
    const float* recW2  = (const float*)d_in[11];
    const float* recb2  = (const float*)d_in[12];
    const float* recW3  = (const float*)d_in[13];
    const float* recb3  = (const float*)d_in[14];
    const float* mlpW1  = (const float*)d_in[15];
    const float* mlpb1  = (const float*)d_in[16];
    const float* mlpW2  = (const float*)d_in[17];
    const float* mlpb2  = (const float*)d_in[18];

    float* out   = (float*)d_out;      // [64*64] out, then [50000*4] x_rec
    float* x_rec = out + 4096;

    char* w = (char*)d_ws;
    u16*   y16    = (u16*)w;    w += (size_t)NN * CH * 2;      // gather output (bf16)
    float* h      = (float*)w;  w += (size_t)NN * CH * 4;      // GEMM1 out (f32, stats)
    u16*   xc     = (u16*)w;    w += (size_t)NN * CH * 2;      // layer output (bf16)
    u16*   r1     = (u16*)w;    w += (size_t)NN * CH * 2;      // rec scratch (bf16)
    u16*   Wt     = (u16*)w;    w += (size_t)9 * 16384 * 2;    // transposed bf16 weights
    float* pstats = (float*)w;  w += (size_t)NGB * 256 * 4;    // fused BN partials
    float* scale  = (float*)w;  w += 128 * 4;
    float* shift  = (float*)w;  w += 128 * 4;
    float* pooled = (float*)w;  w += (size_t)BB * CH * 4;
    int*   deg    = (int*)w;    w += (size_t)NN * 4;
    int*   bsum   = (int*)w;    w += (size_t)NSB * 4;
    int*   rowptr = (int*)w;    w += (size_t)(NN + 1) * 4;
    int*   cur    = (int*)w;    w += (size_t)NN * 4;
    int*   perm   = (int*)w;    w += (size_t)EE * 4;

    dim3 b256(256), b128(128);

    // CSR build (parallel scan)
    k_zero<<<NSB, b256, 0, stream>>>(deg, NN);
    k_count<<<2344, b256, 0, stream>>>(ei, deg);
    k_scanA<<<NSB, b256, 0, stream>>>(deg, bsum);
    k_scanB<<<NSB, b256, 0, stream>>>(deg, bsum, rowptr, cur);
    k_fill<<<2344, b256, 0, stream>>>(ei, cur, perm);
    k_transpose_all<<<576, b256, 0, stream>>>(convW1, convW2, recW1, recW2, recW3, Wt);

    for (int l = 0; l < LL; ++l) {
        if (l == 0)
            k_gather1<<<12500, b256, 0, stream>>>(x_in, rowptr, perm, y16);
        else
            k_gatherB<<<12500, b256, 0, stream>>>(xc, rowptr, perm, y16);
        // GEMM1: h = y @ W1 + b1 (bf16 A -> f32 C), fused BN-stats partials
        k_gemm<8, true, false, false, true, false><<<NGB, b256, 0, stream>>>(
            y16, Wt + l * 16384, convb1 + l * 128, nullptr, nullptr, h, pstats, NN, 128);
        k_bnparam<<<1, b256, 0, stream>>>(pstats, bn_g + l * 128, bn_b + l * 128, scale, shift);
        // GEMM2: xc = relu(relu(BN(h)) @ W2 + b2), BN fused; f32 A -> bf16 C
        k_gemm<8, false, true, true, false, true><<<NGB, b256, 0, stream>>>(
            h, Wt + (3 + l) * 16384, convb2 + l * 128, scale, shift, xc, nullptr, NN, 128);
    }
    // reconstruction head (bf16 chain; rec2 in-place over r1)
    k_gemm<8, true, false, true, false, true><<<NGB, b256, 0, stream>>>(
        xc, Wt + 6 * 16384, recb1, nullptr, nullptr, r1, nullptr, NN, 128);
    k_gemm<8, true, false, true, false, true><<<NGB, b256, 0, stream>>>(
        r1, Wt + 7 * 16384, recb2, nullptr, nullptr, r1, nullptr, NN, 128);
    k_gemm<1, true, false, true, false, false><<<NGB, b256, 0, stream>>>(
        r1, Wt + 8 * 16384, recb3, nullptr, nullptr, x_rec, nullptr, NN, 4);
    // pooling + final MLP (atomic-free)
    k_pool<<<64, b256, 0, stream>>>(xc, batch, pooled);
    k_mlp<<<64, b128, 0, stream>>>(pooled, mlpW1, mlpb1, mlpW2, mlpb2, out);
}

// Round 6
// 501.658 us; speedup vs baseline: 3.9746x; 1.1733x over previous
//
#include <hip/hip_runtime.h>

#define NN 50000
#define EE 600000
#define BB 64
#define CH 128
#define LL 3
#define NGB 391   // GEMM row-blocks = ceil(50000/128), also stats partials
#define NSB 196   // scan blocks = ceil(50000/256)
#define NPB 392   // pool blocks = ceil(50000/128)

typedef unsigned short u16;
typedef unsigned int u32;
typedef short s16x8 __attribute__((ext_vector_type(8)));
typedef float f32x4 __attribute__((ext_vector_type(4)));

__device__ __forceinline__ u16 f2b(float f) {
    u32 x = __float_as_uint(f);
    return (u16)((x + 0x7FFFu + ((x >> 16) & 1u)) >> 16);  // RNE f32->bf16
}
__device__ __forceinline__ float b2f(u16 u) {
    return __uint_as_float(((u32)u) << 16);
}

// ---------------------------------------------------------------------------
// CSR build (edge_index fixed -> rebuild per call; ws is re-poisoned)
// ---------------------------------------------------------------------------
__global__ __launch_bounds__(256) void k_zero(int* __restrict__ p, int n) {
    int i = blockIdx.x * 256 + threadIdx.x;
    if (i < n) p[i] = 0;
}

__global__ __launch_bounds__(256) void k_count(const int* __restrict__ ei,
                                               int* __restrict__ deg) {
    int e = blockIdx.x * 256 + threadIdx.x;
    if (e < EE) atomicAdd(&deg[ei[EE + e]], 1);
}

// stage A: per-block (256 elems) sum of deg -> bsum[blk]
__global__ __launch_bounds__(256) void k_scanA(const int* __restrict__ deg,
                                               int* __restrict__ bsum) {
    __shared__ int sm[256];
    int i = blockIdx.x * 256 + threadIdx.x;
    sm[threadIdx.x] = (i < NN) ? deg[i] : 0;
    __syncthreads();
    for (int off = 128; off > 0; off >>= 1) {
        if (threadIdx.x < off) sm[threadIdx.x] += sm[threadIdx.x + off];
        __syncthreads();
    }
    if (threadIdx.x == 0) bsum[blockIdx.x] = sm[0];
}

// stage B: scan bsum in LDS -> block offset; local scan -> rowptr & cur
__global__ __launch_bounds__(256) void k_scanB(const int* __restrict__ deg,
                                               const int* __restrict__ bsum,
                                               int* __restrict__ rowptr,
                                               int* __restrict__ cur) {
    __shared__ int sb[256], sd[256];
    int t = threadIdx.x;
    sb[t] = (t < NSB) ? bsum[t] : 0;
    __syncthreads();
    for (int off = 1; off < 256; off <<= 1) {
        int v = (t >= off) ? sb[t - off] : 0;
        __syncthreads();
        sb[t] += v;
        __syncthreads();
    }
    int blockOff = (blockIdx.x == 0) ? 0 : sb[blockIdx.x - 1];
    int i = blockIdx.x * 256 + t;
    int d = (i < NN) ? deg[i] : 0;
    sd[t] = d;
    __syncthreads();
    for (int off = 1; off < 256; off <<= 1) {
        int v = (t >= off) ? sd[t - off] : 0;
        __syncthreads();
        sd[t] += v;
        __syncthreads();
    }
    int excl = blockOff + sd[t] - d;
    if (i < NN) { rowptr[i] = excl; cur[i] = excl; }
    if (i == NN - 1) rowptr[NN] = excl + d;
}

__global__ __launch_bounds__(256) void k_fill(const int* __restrict__ ei,
                                              int* __restrict__ cur,
                                              int* __restrict__ perm) {
    int e = blockIdx.x * 256 + threadIdx.x;
    if (e < EE) {
        int dst = ei[EE + e];
        int idx = atomicAdd(&cur[dst], 1);
        perm[idx] = ei[e];
    }
}

// x16 = bf16(x_in), 8 elements/thread. grid 3125 x 256.
__global__ __launch_bounds__(256) void k_cvt(const float* __restrict__ x,
                                             u16* __restrict__ y) {
    long base = (long)(blockIdx.x * 256 + threadIdx.x) * 8;
    if (base < (long)NN * CH) {
        float4 f0 = *(const float4*)(x + base);
        float4 f1 = *(const float4*)(x + base + 4);
        union { u16 pk[8]; uint4 v; } uu;
        uu.pk[0] = f2b(f0.x); uu.pk[1] = f2b(f0.y);
        uu.pk[2] = f2b(f0.z); uu.pk[3] = f2b(f0.w);
        uu.pk[4] = f2b(f1.x); uu.pk[5] = f2b(f1.y);
        uu.pk[6] = f2b(f1.z); uu.pk[7] = f2b(f1.w);
        *(uint4*)(y + base) = uu.v;
    }
}

// ---------------------------------------------------------------------------
// Gather: y[dst] = bf16( x[dst] + sum_{src} x[src] ), bf16 in, f32 accum.
// One wave per dst; 64 perm entries vector-loaded then shfl-broadcast.
// ---------------------------------------------------------------------------
__global__ __launch_bounds__(256) void k_gather(const u16* __restrict__ x,
                                                const int* __restrict__ rowptr,
                                                const int* __restrict__ perm,
                                                u16* __restrict__ y) {
    int dst = blockIdx.x * 4 + (threadIdx.x >> 6);
    if (dst >= NN) return;
    int lane = threadIdx.x & 63;
    int beg = rowptr[dst], end = rowptr[dst + 1];
    int co = lane * 2;
    u32 u0 = *(const u32*)(x + (long)dst * CH + co);
    float2 a = {b2f((u16)(u0 & 0xffff)), b2f((u16)(u0 >> 16))};
    for (int j = beg; j < end; j += 64) {
        int pidx = (j + lane < end) ? perm[j + lane] : 0;
        int cnt = min(64, end - j);
        for (int q = 0; q < cnt; ++q) {
            int src = __shfl(pidx, q);
            u32 uv = *(const u32*)(x + (long)src * CH + co);
            a.x += b2f((u16)(uv & 0xffff));
            a.y += b2f((u16)(uv >> 16));
        }
    }
    u32 pk = ((u32)f2b(a.y) << 16) | (u32)f2b(a.x);
    *(u32*)(y + (long)dst * CH + co) = pk;
}

// ---------------------------------------------------------------------------
// Transpose + convert weights once: Wt[slot][n*128+k] = bf16(W[k][n])
// slots 0-2: convW1[l], 3-5: convW2[l], 6: recW1, 7: recW2, 8: recW3 (zero-pad)
// ---------------------------------------------------------------------------
__global__ __launch_bounds__(256) void k_transpose_all(
    const float* __restrict__ cW1, const float* __restrict__ cW2,
    const float* __restrict__ rW1, const float* __restrict__ rW2,
    const float* __restrict__ rW3, u16* __restrict__ Wt) {
    int idx = blockIdx.x * 256 + threadIdx.x;
    if (idx < 8 * 16384) {
        int slot = idx >> 14;
        int wi = idx & 16383;
        int k = wi >> 7, n = wi & 127;
        const float* src = slot < 3 ? cW1 + slot * 16384
                         : slot < 6 ? cW2 + (slot - 3) * 16384
                         : slot == 6 ? rW1 : rW2;
        Wt[slot * 16384 + n * 128 + k] = f2b(src[wi]);
    } else if (idx < 9 * 16384) {
        int j = idx - 8 * 16384;
        int n = j >> 7, k = j & 127;
        Wt[8 * 16384 + j] = (n < 4) ? f2b(rW3[k * 4 + n]) : (u16)0;
    }
}

// ---------------------------------------------------------------------------
// MFMA GEMM: C[M x ldc] = op(A)[M x 128] @ Wt^T + bias, K = 128.
// ABF16: A stored bf16 (direct stage). BN (f32 A only): relu(scale*a+shift).
// RELU: relu on output. STATS: fused per-block sum/sumsq of C (pre-relu).
// OUTBF16: C stored bf16.  LDS XOR-swizzle chunk c^(r&15); layouts m89/m91.
// In-place safe (block stages all A rows before writing C).
// ---------------------------------------------------------------------------
template <int NT, bool ABF16, bool BN, bool RELU, bool STATS, bool OUTBF16>
__global__ __launch_bounds__(256) void k_gemm(
    const void* __restrict__ Ap, const u16* __restrict__ Wt,
    const float* __restrict__ bias, const float* __restrict__ scale,
    const float* __restrict__ shift, void* __restrict__ Cp,
    float* __restrict__ pstats, int M, int ldc) {
    __shared__ u16 sA[128 * CH];
    __shared__ u16 sB[NT * 16 * CH];
    const int tid = threadIdx.x;
    const int s = tid & 15;
    const int rr = tid >> 4;
    const int r0 = blockIdx.x * 128;

    float sc[8], sh[8];
    if constexpr (BN) {
#pragma unroll
        for (int j = 0; j < 8; ++j) {
            sc[j] = scale[8 * s + j];
            sh[j] = shift[8 * s + j];
        }
    }

#pragma unroll
    for (int it = 0; it < NT; ++it) {
        int n = it * 16 + rr;
        uint4 u = *(const uint4*)(Wt + n * CH + 8 * s);
        int phys = (s ^ (n & 15)) * 8;
        *(uint4*)(&sB[n * CH + phys]) = u;
    }
#pragma unroll
    for (int it = 0; it < 8; ++it) {
        int lr = it * 16 + rr;
        int gr = r0 + lr;
        union { u16 pk[8]; uint4 v; } uu;
        if (gr < M) {
            if constexpr (ABF16) {
                uu.v = *(const uint4*)((const u16*)Ap + (long)gr * CH + 8 * s);
            } else {
                const float* Af = (const float*)Ap + (long)gr * CH + 8 * s;
                float4 f0 = *(const float4*)Af;
                float4 f1 = *(const float4*)(Af + 4);
                float vj[8] = {f0.x, f0.y, f0.z, f0.w, f1.x, f1.y, f1.z, f1.w};
#pragma unroll
                for (int j = 0; j < 8; ++j) {
                    float v = vj[j];
                    if constexpr (BN) v = fmaxf(v * sc[j] + sh[j], 0.f);
                    uu.pk[j] = f2b(v);
                }
            }
        } else {
#pragma unroll
            for (int j = 0; j < 8; ++j) uu.pk[j] = 0;
        }
        int phys = (s ^ (lr & 15)) * 8;
        *(uint4*)(&sA[lr * CH + phys]) = uu.v;
    }
    __syncthreads();

    const int lane = tid & 63;
    const int wv = tid >> 6;
    const int quad = lane >> 4;
    const int l16 = lane & 15;

    f32x4 zero4 = {0.f, 0.f, 0.f, 0.f};
    f32x4 acc[2][NT];
#pragma unroll
    for (int m = 0; m < 2; ++m)
#pragma unroll
        for (int t = 0; t < NT; ++t) acc[m][t] = zero4;

    const u16* pa0 = sA + (wv * 32 + l16) * CH;
    const u16* pa1 = pa0 + 16 * CH;

#pragma unroll
    for (int kc = 0; kc < 4; ++kc) {
        int off = (((kc << 2) | quad) ^ l16) << 3;
        s16x8 a0 = *(const s16x8*)(pa0 + off);
        s16x8 a1 = *(const s16x8*)(pa1 + off);
#pragma unroll
        for (int t = 0; t < NT; ++t) {
            s16x8 bfr = *(const s16x8*)(sB + (t * 16 + l16) * CH + off);
            acc[0][t] = __builtin_amdgcn_mfma_f32_16x16x32_bf16(a0, bfr, acc[0][t], 0, 0, 0);
            acc[1][t] = __builtin_amdgcn_mfma_f32_16x16x32_bf16(a1, bfr, acc[1][t], 0, 0, 0);
        }
    }

    float ss[NT], qq[NT];
    if constexpr (STATS) {
#pragma unroll
        for (int t = 0; t < NT; ++t) { ss[t] = 0.f; qq[t] = 0.f; }
    }

#pragma unroll
    for (int t = 0; t < NT; ++t) {
        int col = t * 16 + l16;
        int bcol = col < ldc ? col : (ldc - 1);
        float bv = bias[bcol];
#pragma unroll
        for (int m = 0; m < 2; ++m) {
            int rbase = r0 + wv * 32 + m * 16 + quad * 4;
#pragma unroll
            for (int r = 0; r < 4; ++r) {
                int row = rbase + r;
                if (row < M && col < ldc) {
                    float v = acc[m][t][r] + bv;
                    if constexpr (STATS) { ss[t] += v; qq[t] += v * v; }
                    if constexpr (RELU) v = fmaxf(v, 0.f);
                    if constexpr (OUTBF16)
                        ((u16*)Cp)[(long)row * ldc + col] = f2b(v);
                    else
                        ((float*)Cp)[(long)row * ldc + col] = v;
                }
            }
        }
    }

    if constexpr (STATS) {
#pragma unroll
        for (int t = 0; t < NT; ++t) {
            ss[t] += __shfl_xor(ss[t], 16);
            ss[t] += __shfl_xor(ss[t], 32);
            qq[t] += __shfl_xor(qq[t], 16);
            qq[t] += __shfl_xor(qq[t], 32);
        }
        float* red = (float*)sA;
        __syncthreads();
        if (lane < 16) {
#pragma unroll
            for (int t = 0; t < NT; ++t) {
                red[wv * 256 + t * 16 + l16] = ss[t];
                red[wv * 256 + 128 + t * 16 + l16] = qq[t];
            }
        }
        __syncthreads();
        float v = red[tid] + red[256 + tid] + red[512 + tid] + red[768 + tid];
        pstats[(long)blockIdx.x * 256 + tid] = v;
    }
}

// BN param: reduce pstats over NGB blocks. scale=g*rstd; shift=b-mu*g*rstd.
__global__ __launch_bounds__(256) void k_bnparam(const float* __restrict__ pstats,
                                                 const float* __restrict__ g,
                                                 const float* __restrict__ b,
                                                 float* __restrict__ scale,
                                                 float* __restrict__ shift) {
    __shared__ float sm[256];
    int t = threadIdx.x;
    float acc = 0.f;
    for (int blk = 0; blk < NGB; ++blk) acc += pstats[blk * 256 + t];
    sm[t] = acc;
    __syncthreads();
    if (t < 128) {
        float mu = sm[t] / (float)NN;
        float var = sm[128 + t] / (float)NN - mu * mu;
        float rstd = rsqrtf(var + 1e-5f);
        float gg = g[t], bb = b[t];
        scale[t] = gg * rstd;
        shift[t] = bb - mu * gg * rstd;
    }
}

// ---------------------------------------------------------------------------
// global_add_pool, parallel: 392 blocks x 128 rows; run-length accumulate in
// the sorted batch; one unsafeAtomicAdd per (run, channel, half).
// pooled must be pre-zeroed. batch reads are uniform per half -> scalar loads.
// ---------------------------------------------------------------------------
__global__ __launch_bounds__(256) void k_pool(const u16* __restrict__ x,
                                              const int* __restrict__ batch,
                                              float* __restrict__ pooled) {
    int r0 = blockIdx.x * 128;
    if (r0 >= NN) return;
    int rend = r0 + 128 < NN ? r0 + 128 : NN;
    int c = threadIdx.x & 127;
    int half = threadIdx.x >> 7;
    int r = r0 + half;
    if (r >= rend) return;
    int g = batch[r];
    float s = 0.f;
    for (; r < rend; r += 2) {
        int gg = batch[r];
        if (gg != g) {
            unsafeAtomicAdd(pooled + g * CH + c, s);
            s = 0.f;
            g = gg;
        }
        s += b2f(x[(long)r * CH + c]);
    }
    unsafeAtomicAdd(pooled + g * CH + c, s);
}

// out[b] = relu(pooled[b] @ W1 + b1) @ W2 + b2  ; grid 64 x 128, all f32
__global__ __launch_bounds__(128) void k_mlp(const float* __restrict__ pooled,
                                             const float* __restrict__ W1,
                                             const float* __restrict__ b1,
                                             const float* __restrict__ W2,
                                             const float* __restrict__ b2,
                                             float* __restrict__ out) {
    __shared__ float p[128], t1[128];
    int b = blockIdx.x, t = threadIdx.x;
    p[t] = pooled[b * CH + t];
    __syncthreads();
    float acc = b1[t];
    for (int k = 0; k < 128; ++k) acc += p[k] * W1[k * 128 + t];
    t1[t] = fmaxf(acc, 0.f);
    __syncthreads();
    if (t < 64) {
        float o = b2[t];
        for (int k = 0; k < 128; ++k) o += t1[k] * W2[k * 64 + t];
        out[b * 64 + t] = o;
    }
}

// ---------------------------------------------------------------------------
extern "C" void kernel_launch(void* const* d_in, const int* in_sizes, int n_in,
                              void* d_out, int out_size, void* d_ws, size_t ws_size,
                              hipStream_t stream) {
    const float* x_in   = (const float*)d_in[0];
    const int*   ei     = (const int*)d_in[1];
    const int*   batch  = (const int*)d_in[2];
    const float* convW1 = (const float*)d_in[3];
    const float* convb1 = (const float*)d_in[4];
    const float* bn_g   = (const float*)d_in[5];
    const float* bn_b   = (const float*)d_in[6];
    const float* convW2 = (const float*)d_in[7];
    const float* convb2 = (const float*)d_in[8];
    const float* recW1  = (const float*)d_in[9];
    const float* recb1  = (const float*)d_in[10];
    const float* recW2  = (const float*)d_in[11];
    const float* recb2  = (const float*)d_in[12];
    const float* recW3  = (const float*)d_in[13];
    const float* recb3  = (const float*)d_in[14];
    const float* mlpW1  = (const float*)d_in[15];
    const float* mlpb1  = (const float*)d_in[16];
    const float* mlpW2  = (const float*)d_in[17];
    const float* mlpb2  = (const float*)d_in[18];

    float* out   = (float*)d_out;      // [64*64] out, then [50000*4] x_rec
    float* x_rec = out + 4096;

    char* w = (char*)d_ws;
    u16*   x16    = (u16*)w;    w += (size_t)NN * CH * 2;      // bf16 copy of x_in
    u16*   y16    = (u16*)w;    w += (size_t)NN * CH * 2;      // gather output (bf16)
    float* h      = (float*)w;  w += (size_t)NN * CH * 4;      // GEMM1 out (f32, stats)
    u16*   xc     = (u16*)w;    w += (size_t)NN * CH * 2;      // layer output (bf16)
    u16*   r1     = (u16*)w;    w += (size_t)NN * CH * 2;      // rec scratch (bf16)
    u16*   Wt     = (u16*)w;    w += (size_t)9 * 16384 * 2;    // transposed bf16 weights
    float* pstats = (float*)w;  w += (size_t)NGB * 256 * 4;    // fused BN partials
    float* scale  = (float*)w;  w += 128 * 4;
    float* shift  = (float*)w;  w += 128 * 4;
    float* pooled = (float*)w;  w += (size_t)BB * CH * 4;
    int*   deg    = (int*)w;    w += (size_t)NN * 4;
    int*   bsum   = (int*)w;    w += (size_t)NSB * 4;
    int*   rowptr = (int*)w;    w += (size_t)(NN + 1) * 4;
    int*   cur    = (int*)w;    w += (size_t)NN * 4;
    int*   perm   = (int*)w;    w += (size_t)EE * 4;

    dim3 b256(256), b128(128);

    // CSR build (parallel scan) + weight transpose + x->bf16 + pooled zero
    k_zero<<<NSB, b256, 0, stream>>>(deg, NN);
    k_zero<<<32, b256, 0, stream>>>((int*)pooled, BB * CH);
    k_count<<<2344, b256, 0, stream>>>(ei, deg);
    k_scanA<<<NSB, b256, 0, stream>>>(deg, bsum);
    k_scanB<<<NSB, b256, 0, stream>>>(deg, bsum, rowptr, cur);
    k_fill<<<2344, b256, 0, stream>>>(ei, cur, perm);
    k_cvt<<<3125, b256, 0, stream>>>(x_in, x16);
    k_transpose_all<<<576, b256, 0, stream>>>(convW1, convW2, recW1, recW2, recW3, Wt);

    const u16* cur_x = x16;
    for (int l = 0; l < LL; ++l) {
        k_gather<<<12500, b256, 0, stream>>>(cur_x, rowptr, perm, y16);
        // GEMM1: h = y @ W1 + b1 (bf16 A -> f32 C), fused BN-stats partials
        k_gemm<8, true, false, false, true, false><<<NGB, b256, 0, stream>>>(
            y16, Wt + l * 16384, convb1 + l * 128, nullptr, nullptr, h, pstats, NN, 128);
        k_bnparam<<<1, b256, 0, stream>>>(pstats, bn_g + l * 128, bn_b + l * 128, scale, shift);
        // GEMM2: xc = relu(relu(BN(h)) @ W2 + b2), BN fused; f32 A -> bf16 C
        k_gemm<8, false, true, true, false, true><<<NGB, b256, 0, stream>>>(
            h, Wt + (3 + l) * 16384, convb2 + l * 128, scale, shift, xc, nullptr, NN, 128);
        cur_x = xc;
    }
    // reconstruction head (bf16 chain; rec2 in-place over r1)
    k_gemm<8, true, false, true, false, true><<<NGB, b256, 0, stream>>>(
        xc, Wt + 6 * 16384, recb1, nullptr, nullptr, r1, nullptr, NN, 128);
    k_gemm<8, true, false, true, false, true><<<NGB, b256, 0, stream>>>(
        r1, Wt + 7 * 16384, recb2, nullptr, nullptr, r1, nullptr, NN, 128);
    k_gemm<1, true, false, true, false, false><<<NGB, b256, 0, stream>>>(
        r1, Wt + 8 * 16384, recb3, nullptr, nullptr, x_rec, nullptr, NN, 4);
    // pooling + final MLP
    k_pool<<<NPB, b256, 0, stream>>>(xc, batch, pooled);
    k_mlp<<<64, b128, 0, stream>>>(pooled, mlpW1, mlpb1, mlpW2, mlpb2, out);
}

// Round 7
// 466.660 us; speedup vs baseline: 4.2727x; 1.0750x over previous
//
#include <hip/hip_runtime.h>

#define NN 50000
#define EE 600000
#define BB 64
#define CH 128
#define LL 3
#define NGB 391   // GEMM row-blocks = ceil(50000/128), also stats partials
#define NSB 196   // scan blocks = ceil(50000/256)
#define NPB 392   // pool blocks = ceil(50000/128)

typedef unsigned short u16;
typedef unsigned int u32;
typedef short s16x8 __attribute__((ext_vector_type(8)));
typedef float f32x4 __attribute__((ext_vector_type(4)));

__device__ __forceinline__ u16 f2b(float f) {
    u32 x = __float_as_uint(f);
    return (u16)((x + 0x7FFFu + ((x >> 16) & 1u)) >> 16);  // RNE f32->bf16
}
__device__ __forceinline__ float b2f(u16 u) {
    return __uint_as_float(((u32)u) << 16);
}

// ---------------------------------------------------------------------------
// CSR build (edge_index fixed -> rebuild per call; ws is re-poisoned)
// ---------------------------------------------------------------------------
__global__ __launch_bounds__(256) void k_zero(int* __restrict__ p, int n) {
    int i = blockIdx.x * 256 + threadIdx.x;
    if (i < n) p[i] = 0;
}

__global__ __launch_bounds__(256) void k_count(const int* __restrict__ ei,
                                               int* __restrict__ deg) {
    int e = blockIdx.x * 256 + threadIdx.x;
    if (e < EE) atomicAdd(&deg[ei[EE + e]], 1);
}

// stage A: per-block (256 elems) sum of deg -> bsum[blk]
__global__ __launch_bounds__(256) void k_scanA(const int* __restrict__ deg,
                                               int* __restrict__ bsum) {
    __shared__ int sm[256];
    int i = blockIdx.x * 256 + threadIdx.x;
    sm[threadIdx.x] = (i < NN) ? deg[i] : 0;
    __syncthreads();
    for (int off = 128; off > 0; off >>= 1) {
        if (threadIdx.x < off) sm[threadIdx.x] += sm[threadIdx.x + off];
        __syncthreads();
    }
    if (threadIdx.x == 0) bsum[blockIdx.x] = sm[0];
}

// stage B: scan bsum in LDS -> block offset; local scan -> rowptr & cur
__global__ __launch_bounds__(256) void k_scanB(const int* __restrict__ deg,
                                               const int* __restrict__ bsum,
                                               int* __restrict__ rowptr,
                                               int* __restrict__ cur) {
    __shared__ int sb[256], sd[256];
    int t = threadIdx.x;
    sb[t] = (t < NSB) ? bsum[t] : 0;
    __syncthreads();
    for (int off = 1; off < 256; off <<= 1) {
        int v = (t >= off) ? sb[t - off] : 0;
        __syncthreads();
        sb[t] += v;
        __syncthreads();
    }
    int blockOff = (blockIdx.x == 0) ? 0 : sb[blockIdx.x - 1];
    int i = blockIdx.x * 256 + t;
    int d = (i < NN) ? deg[i] : 0;
    sd[t] = d;
    __syncthreads();
    for (int off = 1; off < 256; off <<= 1) {
        int v = (t >= off) ? sd[t - off] : 0;
        __syncthreads();
        sd[t] += v;
        __syncthreads();
    }
    int excl = blockOff + sd[t] - d;
    if (i < NN) { rowptr[i] = excl; cur[i] = excl; }
    if (i == NN - 1) rowptr[NN] = excl + d;
}

__global__ __launch_bounds__(256) void k_fill(const int* __restrict__ ei,
                                              int* __restrict__ cur,
                                              int* __restrict__ perm) {
    int e = blockIdx.x * 256 + threadIdx.x;
    if (e < EE) {
        int dst = ei[EE + e];
        int idx = atomicAdd(&cur[dst], 1);
        perm[idx] = ei[e];
    }
}

// x16 = bf16(x_in), 8 elements/thread. grid 3125 x 256.
__global__ __launch_bounds__(256) void k_cvt(const float* __restrict__ x,
                                             u16* __restrict__ y) {
    long base = (long)(blockIdx.x * 256 + threadIdx.x) * 8;
    if (base < (long)NN * CH) {
        float4 f0 = *(const float4*)(x + base);
        float4 f1 = *(const float4*)(x + base + 4);
        union { u16 pk[8]; uint4 v; } uu;
        uu.pk[0] = f2b(f0.x); uu.pk[1] = f2b(f0.y);
        uu.pk[2] = f2b(f0.z); uu.pk[3] = f2b(f0.w);
        uu.pk[4] = f2b(f1.x); uu.pk[5] = f2b(f1.y);
        uu.pk[6] = f2b(f1.z); uu.pk[7] = f2b(f1.w);
        *(uint4*)(y + base) = uu.v;
    }
}

// ---------------------------------------------------------------------------
// Gather: y[dst] = bf16( x[dst] + sum_{src} x[src] ), bf16 in, f32 accum.
// One dst per 16-lane group (4 independent load chains per wave for MLP).
// Lane covers 8 channels: one uint4 per src row; 16 lanes = 256 B coalesced.
// grid 3125 x 256 (16 dst per block).
// ---------------------------------------------------------------------------
__global__ __launch_bounds__(256) void k_gather(const u16* __restrict__ x,
                                                const int* __restrict__ rowptr,
                                                const int* __restrict__ perm,
                                                u16* __restrict__ y) {
    int dst = blockIdx.x * 16 + (threadIdx.x >> 4);
    if (dst >= NN) return;
    int lane = threadIdx.x & 15;
    int co = lane * 8;
    int beg = rowptr[dst], end = rowptr[dst + 1];
    union { u16 pk[8]; uint4 v; } uu;
    uu.v = *(const uint4*)(x + (long)dst * CH + co);
    float a[8];
#pragma unroll
    for (int j = 0; j < 8; ++j) a[j] = b2f(uu.pk[j]);
    for (int e = beg; e < end; ++e) {
        int src = perm[e];
        union { u16 pk[8]; uint4 v; } sv;
        sv.v = *(const uint4*)(x + (long)src * CH + co);
#pragma unroll
        for (int j = 0; j < 8; ++j) a[j] += b2f(sv.pk[j]);
    }
    union { u16 pk[8]; uint4 v; } ov;
#pragma unroll
    for (int j = 0; j < 8; ++j) ov.pk[j] = f2b(a[j]);
    *(uint4*)(y + (long)dst * CH + co) = ov.v;
}

// ---------------------------------------------------------------------------
// Transpose + convert weights once: Wt[slot][n*128+k] = bf16(W[k][n])
// slots 0-2: convW1[l], 3-5: convW2[l], 6: recW1, 7: recW2, 8: recW3 (zero-pad)
// ---------------------------------------------------------------------------
__global__ __launch_bounds__(256) void k_transpose_all(
    const float* __restrict__ cW1, const float* __restrict__ cW2,
    const float* __restrict__ rW1, const float* __restrict__ rW2,
    const float* __restrict__ rW3, u16* __restrict__ Wt) {
    int idx = blockIdx.x * 256 + threadIdx.x;
    if (idx < 8 * 16384) {
        int slot = idx >> 14;
        int wi = idx & 16383;
        int k = wi >> 7, n = wi & 127;
        const float* src = slot < 3 ? cW1 + slot * 16384
                         : slot < 6 ? cW2 + (slot - 3) * 16384
                         : slot == 6 ? rW1 : rW2;
        Wt[slot * 16384 + n * 128 + k] = f2b(src[wi]);
    } else if (idx < 9 * 16384) {
        int j = idx - 8 * 16384;
        int n = j >> 7, k = j & 127;
        Wt[8 * 16384 + j] = (n < 4) ? f2b(rW3[k * 4 + n]) : (u16)0;
    }
}

// ---------------------------------------------------------------------------
// MFMA GEMM: C[M x ldc] = op(A)[M x 128] @ Wt^T + bias, K = 128.
// ABF16: A stored bf16. BN: relu(scale*a+shift) fused into A staging (both
// f32 and bf16 A). RELU: relu on output. STATS: fused per-block sum/sumsq of
// C (pre-relu, from f32 accumulators). OUTBF16: C stored bf16.
// LDS XOR-swizzle chunk c^(r&15); layouts verified m89/m91.
// In-place safe (block stages all A rows before writing C).
// ---------------------------------------------------------------------------
template <int NT, bool ABF16, bool BN, bool RELU, bool STATS, bool OUTBF16>
__global__ __launch_bounds__(256) void k_gemm(
    const void* __restrict__ Ap, const u16* __restrict__ Wt,
    const float* __restrict__ bias, const float* __restrict__ scale,
    const float* __restrict__ shift, void* __restrict__ Cp,
    float* __restrict__ pstats, int M, int ldc) {
    __shared__ u16 sA[128 * CH];
    __shared__ u16 sB[NT * 16 * CH];
    const int tid = threadIdx.x;
    const int s = tid & 15;
    const int rr = tid >> 4;
    const int r0 = blockIdx.x * 128;

    float sc[8], sh[8];
    if constexpr (BN) {
#pragma unroll
        for (int j = 0; j < 8; ++j) {
            sc[j] = scale[8 * s + j];
            sh[j] = shift[8 * s + j];
        }
    }

#pragma unroll
    for (int it = 0; it < NT; ++it) {
        int n = it * 16 + rr;
        uint4 u = *(const uint4*)(Wt + n * CH + 8 * s);
        int phys = (s ^ (n & 15)) * 8;
        *(uint4*)(&sB[n * CH + phys]) = u;
    }
#pragma unroll
    for (int it = 0; it < 8; ++it) {
        int lr = it * 16 + rr;
        int gr = r0 + lr;
        union { u16 pk[8]; uint4 v; } uu;
        if (gr < M) {
            if constexpr (ABF16) {
                uu.v = *(const uint4*)((const u16*)Ap + (long)gr * CH + 8 * s);
                if constexpr (BN) {
#pragma unroll
                    for (int j = 0; j < 8; ++j) {
                        float v = fmaxf(b2f(uu.pk[j]) * sc[j] + sh[j], 0.f);
                        uu.pk[j] = f2b(v);
                    }
                }
            } else {
                const float* Af = (const float*)Ap + (long)gr * CH + 8 * s;
                float4 f0 = *(const float4*)Af;
                float4 f1 = *(const float4*)(Af + 4);
                float vj[8] = {f0.x, f0.y, f0.z, f0.w, f1.x, f1.y, f1.z, f1.w};
#pragma unroll
                for (int j = 0; j < 8; ++j) {
                    float v = vj[j];
                    if constexpr (BN) v = fmaxf(v * sc[j] + sh[j], 0.f);
                    uu.pk[j] = f2b(v);
                }
            }
        } else {
#pragma unroll
            for (int j = 0; j < 8; ++j) uu.pk[j] = 0;
        }
        int phys = (s ^ (lr & 15)) * 8;
        *(uint4*)(&sA[lr * CH + phys]) = uu.v;
    }
    __syncthreads();

    const int lane = tid & 63;
    const int wv = tid >> 6;
    const int quad = lane >> 4;
    const int l16 = lane & 15;

    f32x4 zero4 = {0.f, 0.f, 0.f, 0.f};
    f32x4 acc[2][NT];
#pragma unroll
    for (int m = 0; m < 2; ++m)
#pragma unroll
        for (int t = 0; t < NT; ++t) acc[m][t] = zero4;

    const u16* pa0 = sA + (wv * 32 + l16) * CH;
    const u16* pa1 = pa0 + 16 * CH;

#pragma unroll
    for (int kc = 0; kc < 4; ++kc) {
        int off = (((kc << 2) | quad) ^ l16) << 3;
        s16x8 a0 = *(const s16x8*)(pa0 + off);
        s16x8 a1 = *(const s16x8*)(pa1 + off);
#pragma unroll
        for (int t = 0; t < NT; ++t) {
            s16x8 bfr = *(const s16x8*)(sB + (t * 16 + l16) * CH + off);
            acc[0][t] = __builtin_amdgcn_mfma_f32_16x16x32_bf16(a0, bfr, acc[0][t], 0, 0, 0);
            acc[1][t] = __builtin_amdgcn_mfma_f32_16x16x32_bf16(a1, bfr, acc[1][t], 0, 0, 0);
        }
    }

    float ss[NT], qq[NT];
    if constexpr (STATS) {
#pragma unroll
        for (int t = 0; t < NT; ++t) { ss[t] = 0.f; qq[t] = 0.f; }
    }

#pragma unroll
    for (int t = 0; t < NT; ++t) {
        int col = t * 16 + l16;
        int bcol = col < ldc ? col : (ldc - 1);
        float bv = bias[bcol];
#pragma unroll
        for (int m = 0; m < 2; ++m) {
            int rbase = r0 + wv * 32 + m * 16 + quad * 4;
#pragma unroll
            for (int r = 0; r < 4; ++r) {
                int row = rbase + r;
                if (row < M && col < ldc) {
                    float v = acc[m][t][r] + bv;
                    if constexpr (STATS) { ss[t] += v; qq[t] += v * v; }
                    if constexpr (RELU) v = fmaxf(v, 0.f);
                    if constexpr (OUTBF16)
                        ((u16*)Cp)[(long)row * ldc + col] = f2b(v);
                    else
                        ((float*)Cp)[(long)row * ldc + col] = v;
                }
            }
        }
    }

    if constexpr (STATS) {
#pragma unroll
        for (int t = 0; t < NT; ++t) {
            ss[t] += __shfl_xor(ss[t], 16);
            ss[t] += __shfl_xor(ss[t], 32);
            qq[t] += __shfl_xor(qq[t], 16);
            qq[t] += __shfl_xor(qq[t], 32);
        }
        float* red = (float*)sA;
        __syncthreads();
        if (lane < 16) {
#pragma unroll
            for (int t = 0; t < NT; ++t) {
                red[wv * 256 + t * 16 + l16] = ss[t];
                red[wv * 256 + 128 + t * 16 + l16] = qq[t];
            }
        }
        __syncthreads();
        float v = red[tid] + red[256 + tid] + red[512 + tid] + red[768 + tid];
        pstats[(long)blockIdx.x * 256 + tid] = v;
    }
}

// BN param: reduce pstats over NGB blocks. scale=g*rstd; shift=b-mu*g*rstd.
__global__ __launch_bounds__(256) void k_bnparam(const float* __restrict__ pstats,
                                                 const float* __restrict__ g,
                                                 const float* __restrict__ b,
                                                 float* __restrict__ scale,
                                                 float* __restrict__ shift) {
    __shared__ float sm[256];
    int t = threadIdx.x;
    float acc = 0.f;
    for (int blk = 0; blk < NGB; ++blk) acc += pstats[blk * 256 + t];
    sm[t] = acc;
    __syncthreads();
    if (t < 128) {
        float mu = sm[t] / (float)NN;
        float var = sm[128 + t] / (float)NN - mu * mu;
        float rstd = rsqrtf(var + 1e-5f);
        float gg = g[t], bb = b[t];
        scale[t] = gg * rstd;
        shift[t] = bb - mu * gg * rstd;
    }
}

// ---------------------------------------------------------------------------
// global_add_pool, parallel: 392 blocks x 128 rows; run-length accumulate in
// the sorted batch; one unsafeAtomicAdd per (run, channel, half).
// ---------------------------------------------------------------------------
__global__ __launch_bounds__(256) void k_pool(const u16* __restrict__ x,
                                              const int* __restrict__ batch,
                                              float* __restrict__ pooled) {
    int r0 = blockIdx.x * 128;
    if (r0 >= NN) return;
    int rend = r0 + 128 < NN ? r0 + 128 : NN;
    int c = threadIdx.x & 127;
    int half = threadIdx.x >> 7;
    int r = r0 + half;
    if (r >= rend) return;
    int g = batch[r];
    float s = 0.f;
    for (; r < rend; r += 2) {
        int gg = batch[r];
        if (gg != g) {
            unsafeAtomicAdd(pooled + g * CH + c, s);
            s = 0.f;
            g = gg;
        }
        s += b2f(x[(long)r * CH + c]);
    }
    unsafeAtomicAdd(pooled + g * CH + c, s);
}

// out[b] = relu(pooled[b] @ W1 + b1) @ W2 + b2  ; grid 64 x 128, all f32
__global__ __launch_bounds__(128) void k_mlp(const float* __restrict__ pooled,
                                             const float* __restrict__ W1,
                                             const float* __restrict__ b1,
                                             const float* __restrict__ W2,
                                             const float* __restrict__ b2,
                                             float* __restrict__ out) {
    __shared__ float p[128], t1[128];
    int b = blockIdx.x, t = threadIdx.x;
    p[t] = pooled[b * CH + t];
    __syncthreads();
    float acc = b1[t];
    for (int k = 0; k < 128; ++k) acc += p[k] * W1[k * 128 + t];
    t1[t] = fmaxf(acc, 0.f);
    __syncthreads();
    if (t < 64) {
        float o = b2[t];
        for (int k = 0; k < 128; ++k) o += t1[k] * W2[k * 64 + t];
        out[b * 64 + t] = o;
    }
}

// ---------------------------------------------------------------------------
extern "C" void kernel_launch(void* const* d_in, const int* in_sizes, int n_in,
                              void* d_out, int out_size, void* d_ws, size_t ws_size,
                              hipStream_t stream) {
    const float* x_in   = (const float*)d_in[0];
    const int*   ei     = (const int*)d_in[1];
    const int*   batch  = (const int*)d_in[2];
    const float* convW1 = (const float*)d_in[3];
    const float* convb1 = (const float*)d_in[4];
    const float* bn_g   = (const float*)d_in[5];
    const float* bn_b   = (const float*)d_in[6];
    const float* convW2 = (const float*)d_in[7];
    const float* convb2 = (const float*)d_in[8];
    const float* recW1  = (const float*)d_in[9];
    const float* recb1  = (const float*)d_in[10];
    const float* recW2  = (const float*)d_in[11];
    const float* recb2  = (const float*)d_in[12];
    const float* recW3  = (const float*)d_in[13];
    const float* recb3  = (const float*)d_in[14];
    const float* mlpW1  = (const float*)d_in[15];
    const float* mlpb1  = (const float*)d_in[16];
    const float* mlpW2  = (const float*)d_in[17];
    const float* mlpb2  = (const float*)d_in[18];

    float* out   = (float*)d_out;      // [64*64] out, then [50000*4] x_rec
    float* x_rec = out + 4096;

    char* w = (char*)d_ws;
    u16*   x16    = (u16*)w;    w += (size_t)NN * CH * 2;      // bf16 copy of x_in
    u16*   y16    = (u16*)w;    w += (size_t)NN * CH * 2;      // gather output (bf16)
    u16*   h16    = (u16*)w;    w += (size_t)NN * CH * 2;      // GEMM1 out (bf16)
    u16*   xc     = (u16*)w;    w += (size_t)NN * CH * 2;      // layer output (bf16)
    u16*   r1     = (u16*)w;    w += (size_t)NN * CH * 2;      // rec scratch (bf16)
    u16*   Wt     = (u16*)w;    w += (size_t)9 * 16384 * 2;    // transposed bf16 weights
    float* pstats = (float*)w;  w += (size_t)NGB * 256 * 4;    // fused BN partials
    float* scale  = (float*)w;  w += 128 * 4;
    float* shift  = (float*)w;  w += 128 * 4;
    float* pooled = (float*)w;  w += (size_t)BB * CH * 4;
    int*   deg    = (int*)w;    w += (size_t)NN * 4;
    int*   bsum   = (int*)w;    w += (size_t)NSB * 4;
    int*   rowptr = (int*)w;    w += (size_t)(NN + 1) * 4;
    int*   cur    = (int*)w;    w += (size_t)NN * 4;
    int*   perm   = (int*)w;    w += (size_t)EE * 4;

    dim3 b256(256), b128(128);

    // CSR build (parallel scan) + weight transpose + x->bf16 + pooled zero
    k_zero<<<NSB, b256, 0, stream>>>(deg, NN);
    k_zero<<<32, b256, 0, stream>>>((int*)pooled, BB * CH);
    k_count<<<2344, b256, 0, stream>>>(ei, deg);
    k_scanA<<<NSB, b256, 0, stream>>>(deg, bsum);
    k_scanB<<<NSB, b256, 0, stream>>>(deg, bsum, rowptr, cur);
    k_fill<<<2344, b256, 0, stream>>>(ei, cur, perm);
    k_cvt<<<3125, b256, 0, stream>>>(x_in, x16);
    k_transpose_all<<<576, b256, 0, stream>>>(convW1, convW2, recW1, recW2, recW3, Wt);

    const u16* cur_x = x16;
    for (int l = 0; l < LL; ++l) {
        k_gather<<<3125, b256, 0, stream>>>(cur_x, rowptr, perm, y16);
        // GEMM1: h = y @ W1 + b1 (bf16 A -> bf16 C), fused BN-stats partials
        k_gemm<8, true, false, false, true, true><<<NGB, b256, 0, stream>>>(
            y16, Wt + l * 16384, convb1 + l * 128, nullptr, nullptr, h16, pstats, NN, 128);
        k_bnparam<<<1, b256, 0, stream>>>(pstats, bn_g + l * 128, bn_b + l * 128, scale, shift);
        // GEMM2: xc = relu(relu(BN(h)) @ W2 + b2), BN fused; bf16 A -> bf16 C
        k_gemm<8, true, true, true, false, true><<<NGB, b256, 0, stream>>>(
            h16, Wt + (3 + l) * 16384, convb2 + l * 128, scale, shift, xc, nullptr, NN, 128);
        cur_x = xc;
    }
    // reconstruction head (bf16 chain; rec2 in-place over r1)
    k_gemm<8, true, false, true, false, true><<<NGB, b256, 0, stream>>>(
        xc, Wt + 6 * 16384, recb1, nullptr, nullptr, r1, nullptr, NN, 128);
    k_gemm<8, true, false, true, false, true><<<NGB, b256, 0, stream>>>(
        r1, Wt + 7 * 16384, recb2, nullptr, nullptr, r1, nullptr, NN, 128);
    k_gemm<1, true, false, true, false, false><<<NGB, b256, 0, stream>>>(
        r1, Wt + 8 * 16384, recb3, nullptr, nullptr, x_rec, nullptr, NN, 4);
    // pooling + final MLP
    k_pool<<<NPB, b256, 0, stream>>>(xc, batch, pooled);
    k_mlp<<<64, b128, 0, stream>>>(pooled, mlpW1, mlpb1, mlpW2, mlpb2, out);
}

// Round 8
// 431.625 us; speedup vs baseline: 4.6195x; 1.0812x over previous
//
#include <hip/hip_runtime.h>

#define NN 50000
#define EE 600000
#define BB 64
#define CH 128
#define LL 3
#define NGB 391   // GEMM row-blocks = ceil(50000/128), also stats partials
#define NSB 196   // scan blocks = ceil(50000/256)
#define NPB 392   // pool blocks = ceil(50000/128)

typedef unsigned short u16;
typedef unsigned int u32;
typedef short s16x8 __attribute__((ext_vector_type(8)));
typedef float f32x4 __attribute__((ext_vector_type(4)));

__device__ __forceinline__ u16 f2b(float f) {
    u32 x = __float_as_uint(f);
    return (u16)((x + 0x7FFFu + ((x >> 16) & 1u)) >> 16);  // RNE f32->bf16
}
__device__ __forceinline__ float b2f(u16 u) {
    return __uint_as_float(((u32)u) << 16);
}

// ---------------------------------------------------------------------------
// CSR build (edge_index fixed -> rebuild per call; ws is re-poisoned)
// ---------------------------------------------------------------------------
__global__ __launch_bounds__(256) void k_zero2(int* __restrict__ deg,
                                               float* __restrict__ pooled) {
    int i = blockIdx.x * 256 + threadIdx.x;
    if (i < NN) deg[i] = 0;
    int j = i - NN;
    if (j >= 0 && j < BB * CH) pooled[j] = 0.f;
}

__global__ __launch_bounds__(256) void k_count(const int* __restrict__ ei,
                                               int* __restrict__ deg) {
    int e = blockIdx.x * 256 + threadIdx.x;
    if (e < EE) atomicAdd(&deg[ei[EE + e]], 1);
}

// stage A: per-block (256 elems) sum of deg -> bsum[blk]
__global__ __launch_bounds__(256) void k_scanA(const int* __restrict__ deg,
                                               int* __restrict__ bsum) {
    __shared__ int sm[256];
    int i = blockIdx.x * 256 + threadIdx.x;
    sm[threadIdx.x] = (i < NN) ? deg[i] : 0;
    __syncthreads();
    for (int off = 128; off > 0; off >>= 1) {
        if (threadIdx.x < off) sm[threadIdx.x] += sm[threadIdx.x + off];
        __syncthreads();
    }
    if (threadIdx.x == 0) bsum[blockIdx.x] = sm[0];
}

// stage B: scan bsum in LDS -> block offset; local scan -> rowptr & cur
__global__ __launch_bounds__(256) void k_scanB(const int* __restrict__ deg,
                                               const int* __restrict__ bsum,
                                               int* __restrict__ rowptr,
                                               int* __restrict__ cur) {
    __shared__ int sb[256], sd[256];
    int t = threadIdx.x;
    sb[t] = (t < NSB) ? bsum[t] : 0;
    __syncthreads();
    for (int off = 1; off < 256; off <<= 1) {
        int v = (t >= off) ? sb[t - off] : 0;
        __syncthreads();
        sb[t] += v;
        __syncthreads();
    }
    int blockOff = (blockIdx.x == 0) ? 0 : sb[blockIdx.x - 1];
    int i = blockIdx.x * 256 + t;
    int d = (i < NN) ? deg[i] : 0;
    sd[t] = d;
    __syncthreads();
    for (int off = 1; off < 256; off <<= 1) {
        int v = (t >= off) ? sd[t - off] : 0;
        __syncthreads();
        sd[t] += v;
        __syncthreads();
    }
    int excl = blockOff + sd[t] - d;
    if (i < NN) { rowptr[i] = excl; cur[i] = excl; }
    if (i == NN - 1) rowptr[NN] = excl + d;
}

__global__ __launch_bounds__(256) void k_fill(const int* __restrict__ ei,
                                              int* __restrict__ cur,
                                              int* __restrict__ perm) {
    int e = blockIdx.x * 256 + threadIdx.x;
    if (e < EE) {
        int dst = ei[EE + e];
        int idx = atomicAdd(&cur[dst], 1);
        perm[idx] = ei[e];
    }
}

// x16 = bf16(x_in), 8 elements/thread. grid 3125 x 256.
__global__ __launch_bounds__(256) void k_cvt(const float* __restrict__ x,
                                             u16* __restrict__ y) {
    long base = (long)(blockIdx.x * 256 + threadIdx.x) * 8;
    if (base < (long)NN * CH) {
        float4 f0 = *(const float4*)(x + base);
        float4 f1 = *(const float4*)(x + base + 4);
        union { u16 pk[8]; uint4 v; } uu;
        uu.pk[0] = f2b(f0.x); uu.pk[1] = f2b(f0.y);
        uu.pk[2] = f2b(f0.z); uu.pk[3] = f2b(f0.w);
        uu.pk[4] = f2b(f1.x); uu.pk[5] = f2b(f1.y);
        uu.pk[6] = f2b(f1.z); uu.pk[7] = f2b(f1.w);
        *(uint4*)(y + base) = uu.v;
    }
}

// ---------------------------------------------------------------------------
// Gather: y[dst] = bf16( x[dst] + sum_{src} x[src] ), bf16 in, f32 accum.
// One dst per 16-lane group; 2-way unrolled edge loop (2 independent
// accumulator chains -> 2x outstanding loads on this latency-bound kernel).
// ---------------------------------------------------------------------------
__global__ __launch_bounds__(256) void k_gather(const u16* __restrict__ x,
                                                const int* __restrict__ rowptr,
                                                const int* __restrict__ perm,
                                                u16* __restrict__ y) {
    int dst = blockIdx.x * 16 + (threadIdx.x >> 4);
    if (dst >= NN) return;
    int lane = threadIdx.x & 15;
    int co = lane * 8;
    int beg = rowptr[dst], end = rowptr[dst + 1];
    union { u16 pk[8]; uint4 v; } uu;
    uu.v = *(const uint4*)(x + (long)dst * CH + co);
    float a[8], b[8];
#pragma unroll
    for (int j = 0; j < 8; ++j) { a[j] = b2f(uu.pk[j]); b[j] = 0.f; }
    int e = beg;
    for (; e + 1 < end; e += 2) {
        int s0 = perm[e], s1 = perm[e + 1];
        union { u16 pk[8]; uint4 v; } v0, v1;
        v0.v = *(const uint4*)(x + (long)s0 * CH + co);
        v1.v = *(const uint4*)(x + (long)s1 * CH + co);
#pragma unroll
        for (int j = 0; j < 8; ++j) { a[j] += b2f(v0.pk[j]); b[j] += b2f(v1.pk[j]); }
    }
    if (e < end) {
        int s0 = perm[e];
        union { u16 pk[8]; uint4 v; } v0;
        v0.v = *(const uint4*)(x + (long)s0 * CH + co);
#pragma unroll
        for (int j = 0; j < 8; ++j) a[j] += b2f(v0.pk[j]);
    }
    union { u16 pk[8]; uint4 v; } ov;
#pragma unroll
    for (int j = 0; j < 8; ++j) ov.pk[j] = f2b(a[j] + b[j]);
    *(uint4*)(y + (long)dst * CH + co) = ov.v;
}

// ---------------------------------------------------------------------------
// Transpose + convert weights once: Wt[slot][n*128+k] = bf16(W[k][n])
// slots 0-2: convW1[l], 3-5: convW2[l], 6: recW1, 7: recW2, 8: recW3 (zero-pad)
// ---------------------------------------------------------------------------
__global__ __launch_bounds__(256) void k_transpose_all(
    const float* __restrict__ cW1, const float* __restrict__ cW2,
    const float* __restrict__ rW1, const float* __restrict__ rW2,
    const float* __restrict__ rW3, u16* __restrict__ Wt) {
    int idx = blockIdx.x * 256 + threadIdx.x;
    if (idx < 8 * 16384) {
        int slot = idx >> 14;
        int wi = idx & 16383;
        int k = wi >> 7, n = wi & 127;
        const float* src = slot < 3 ? cW1 + slot * 16384
                         : slot < 6 ? cW2 + (slot - 3) * 16384
                         : slot == 6 ? rW1 : rW2;
        Wt[slot * 16384 + n * 128 + k] = f2b(src[wi]);
    } else if (idx < 9 * 16384) {
        int j = idx - 8 * 16384;
        int n = j >> 7, k = j & 127;
        Wt[8 * 16384 + j] = (n < 4) ? f2b(rW3[k * 4 + n]) : (u16)0;
    }
}

// ---------------------------------------------------------------------------
// Shared GEMM building blocks (layouts verified m89/m91; XOR-swizzle c^(r&15))
// ---------------------------------------------------------------------------
__device__ __forceinline__ void stageB8(const u16* __restrict__ Wt, u16* sB,
                                        int s, int rr) {
#pragma unroll
    for (int it = 0; it < 8; ++it) {
        int n = it * 16 + rr;
        uint4 u = *(const uint4*)(Wt + n * CH + 8 * s);
        *(uint4*)(&sB[n * CH + ((s ^ (n & 15)) * 8)]) = u;
    }
}

__device__ __forceinline__ void mfma8(const u16* sA, const u16* sB,
                                      f32x4 acc[2][8], int wv, int quad, int l16) {
    f32x4 z = {0.f, 0.f, 0.f, 0.f};
#pragma unroll
    for (int m = 0; m < 2; ++m)
#pragma unroll
        for (int t = 0; t < 8; ++t) acc[m][t] = z;
    const u16* pa0 = sA + (wv * 32 + l16) * CH;
    const u16* pa1 = pa0 + 16 * CH;
#pragma unroll
    for (int kc = 0; kc < 4; ++kc) {
        int off = (((kc << 2) | quad) ^ l16) << 3;
        s16x8 a0 = *(const s16x8*)(pa0 + off);
        s16x8 a1 = *(const s16x8*)(pa1 + off);
#pragma unroll
        for (int t = 0; t < 8; ++t) {
            s16x8 bfr = *(const s16x8*)(sB + (t * 16 + l16) * CH + off);
            acc[0][t] = __builtin_amdgcn_mfma_f32_16x16x32_bf16(a0, bfr, acc[0][t], 0, 0, 0);
            acc[1][t] = __builtin_amdgcn_mfma_f32_16x16x32_bf16(a1, bfr, acc[1][t], 0, 0, 0);
        }
    }
}

__device__ __forceinline__ void biasrelu(f32x4 acc[2][8],
                                         const float* __restrict__ bias, int l16) {
#pragma unroll
    for (int t = 0; t < 8; ++t) {
        float bv = bias[t * 16 + l16];
#pragma unroll
        for (int m = 0; m < 2; ++m)
#pragma unroll
            for (int r = 0; r < 4; ++r)
                acc[m][t][r] = fmaxf(acc[m][t][r] + bv, 0.f);
    }
}

// write C tile (held in acc, already bias/relu'd) back into sA as bf16 with
// the same XOR-swizzle the A-read expects. C/D: col=t*16+l16, row=quad*4+r.
__device__ __forceinline__ void restage(const f32x4 acc[2][8], u16* sA,
                                        int wv, int quad, int l16) {
#pragma unroll
    for (int t = 0; t < 8; ++t) {
        int chunk = (t << 1) | (l16 >> 3);  // logical 8-elem chunk = col>>3
        int o7 = l16 & 7;
#pragma unroll
        for (int m = 0; m < 2; ++m)
#pragma unroll
            for (int r = 0; r < 4; ++r) {
                int lr = wv * 32 + m * 16 + quad * 4 + r;
                sA[lr * CH + ((chunk ^ (lr & 15)) << 3) + o7] = f2b(acc[m][t][r]);
            }
    }
}

// ---------------------------------------------------------------------------
// MFMA GEMM: C[M x 128] = op(A)[M x 128] @ Wt^T + bias.
// ABF16: A stored bf16. BN: relu(scale*a+shift) fused into A staging.
// RELU: relu on output. STATS: fused per-block sum/sumsq of C (pre-relu).
// OUTBF16: C stored bf16.
// ---------------------------------------------------------------------------
template <bool ABF16, bool BN, bool RELU, bool STATS, bool OUTBF16>
__global__ __launch_bounds__(256) void k_gemm(
    const void* __restrict__ Ap, const u16* __restrict__ Wt,
    const float* __restrict__ bias, const float* __restrict__ scale,
    const float* __restrict__ shift, void* __restrict__ Cp,
    float* __restrict__ pstats, int M) {
    __shared__ u16 sA[128 * CH];
    __shared__ u16 sB[128 * CH];
    const int tid = threadIdx.x;
    const int s = tid & 15;
    const int rr = tid >> 4;
    const int r0 = blockIdx.x * 128;

    float sc[8], sh[8];
    if constexpr (BN) {
#pragma unroll
        for (int j = 0; j < 8; ++j) {
            sc[j] = scale[8 * s + j];
            sh[j] = shift[8 * s + j];
        }
    }

    stageB8(Wt, sB, s, rr);
#pragma unroll
    for (int it = 0; it < 8; ++it) {
        int lr = it * 16 + rr;
        int gr = r0 + lr;
        union { u16 pk[8]; uint4 v; } uu;
        if (gr < M) {
            if constexpr (ABF16) {
                uu.v = *(const uint4*)((const u16*)Ap + (long)gr * CH + 8 * s);
                if constexpr (BN) {
#pragma unroll
                    for (int j = 0; j < 8; ++j)
                        uu.pk[j] = f2b(fmaxf(b2f(uu.pk[j]) * sc[j] + sh[j], 0.f));
                }
            } else {
                const float* Af = (const float*)Ap + (long)gr * CH + 8 * s;
                float4 f0 = *(const float4*)Af;
                float4 f1 = *(const float4*)(Af + 4);
                float vj[8] = {f0.x, f0.y, f0.z, f0.w, f1.x, f1.y, f1.z, f1.w};
#pragma unroll
                for (int j = 0; j < 8; ++j) {
                    float v = vj[j];
                    if constexpr (BN) v = fmaxf(v * sc[j] + sh[j], 0.f);
                    uu.pk[j] = f2b(v);
                }
            }
        } else {
#pragma unroll
            for (int j = 0; j < 8; ++j) uu.pk[j] = 0;
        }
        *(uint4*)(&sA[lr * CH + ((s ^ (lr & 15)) * 8)]) = uu.v;
    }
    __syncthreads();

    const int lane = tid & 63;
    const int wv = tid >> 6;
    const int quad = lane >> 4;
    const int l16 = lane & 15;

    f32x4 acc[2][8];
    mfma8(sA, sB, acc, wv, quad, l16);

    float ss[8], qq[8];
    if constexpr (STATS) {
#pragma unroll
        for (int t = 0; t < 8; ++t) { ss[t] = 0.f; qq[t] = 0.f; }
    }

#pragma unroll
    for (int t = 0; t < 8; ++t) {
        int col = t * 16 + l16;
        float bv = bias[col];
#pragma unroll
        for (int m = 0; m < 2; ++m) {
            int rbase = r0 + wv * 32 + m * 16 + quad * 4;
#pragma unroll
            for (int r = 0; r < 4; ++r) {
                int row = rbase + r;
                if (row < M) {
                    float v = acc[m][t][r] + bv;
                    if constexpr (STATS) { ss[t] += v; qq[t] += v * v; }
                    if constexpr (RELU) v = fmaxf(v, 0.f);
                    if constexpr (OUTBF16)
                        ((u16*)Cp)[(long)row * CH + col] = f2b(v);
                    else
                        ((float*)Cp)[(long)row * CH + col] = v;
                }
            }
        }
    }

    if constexpr (STATS) {
#pragma unroll
        for (int t = 0; t < 8; ++t) {
            ss[t] += __shfl_xor(ss[t], 16);
            ss[t] += __shfl_xor(ss[t], 32);
            qq[t] += __shfl_xor(qq[t], 16);
            qq[t] += __shfl_xor(qq[t], 32);
        }
        float* red = (float*)sA;
        __syncthreads();
        if (lane < 16) {
#pragma unroll
            for (int t = 0; t < 8; ++t) {
                red[wv * 256 + t * 16 + l16] = ss[t];
                red[wv * 256 + 128 + t * 16 + l16] = qq[t];
            }
        }
        __syncthreads();
        float v = red[tid] + red[256 + tid] + red[512 + tid] + red[768 + tid];
        pstats[(long)blockIdx.x * 256 + tid] = v;
    }
}

// ---------------------------------------------------------------------------
// Fused tail: xc = relu(BN(h)@W2l3+b)  [written out for pool]
//   -> rec1 = relu(xc@W6+rb1) -> rec2 = relu(rec1@W7+rb2)
//   -> x_rec = relu(rec2@W8+rb3)   all tile-resident (restage C into sA).
// ---------------------------------------------------------------------------
__global__ __launch_bounds__(256) void k_tail(
    const u16* __restrict__ h16, const u16* __restrict__ Wt,
    const float* __restrict__ cb2, const float* __restrict__ scale,
    const float* __restrict__ shift, const float* __restrict__ rb1,
    const float* __restrict__ rb2, const float* __restrict__ rb3,
    u16* __restrict__ xc, float* __restrict__ x_rec) {
    __shared__ u16 sA[128 * CH];
    __shared__ u16 sB[128 * CH];
    const int tid = threadIdx.x;
    const int s = tid & 15, rr = tid >> 4;
    const int r0 = blockIdx.x * 128;
    const int lane = tid & 63, wv = tid >> 6, quad = lane >> 4, l16 = lane & 15;

    // ---- phase 1: GEMM2 (layer 3) with fused BN on A ----
    float sc[8], sh[8];
#pragma unroll
    for (int j = 0; j < 8; ++j) { sc[j] = scale[8 * s + j]; sh[j] = shift[8 * s + j]; }
    stageB8(Wt + 5 * 16384, sB, s, rr);
#pragma unroll
    for (int it = 0; it < 8; ++it) {
        int lr = it * 16 + rr, gr = r0 + lr;
        union { u16 pk[8]; uint4 v; } uu;
        if (gr < NN) {
            uu.v = *(const uint4*)(h16 + (long)gr * CH + 8 * s);
#pragma unroll
            for (int j = 0; j < 8; ++j)
                uu.pk[j] = f2b(fmaxf(b2f(uu.pk[j]) * sc[j] + sh[j], 0.f));
        } else {
#pragma unroll
            for (int j = 0; j < 8; ++j) uu.pk[j] = 0;
        }
        *(uint4*)(&sA[lr * CH + ((s ^ (lr & 15)) * 8)]) = uu.v;
    }
    __syncthreads();
    f32x4 acc[2][8];
    mfma8(sA, sB, acc, wv, quad, l16);
    biasrelu(acc, cb2, l16);
    // write xc (needed by pool)
#pragma unroll
    for (int t = 0; t < 8; ++t) {
        int col = t * 16 + l16;
#pragma unroll
        for (int m = 0; m < 2; ++m)
#pragma unroll
            for (int r = 0; r < 4; ++r) {
                int row = r0 + wv * 32 + m * 16 + quad * 4 + r;
                if (row < NN) xc[(long)row * CH + col] = f2b(acc[m][t][r]);
            }
    }
    // ---- phase 2: rec1 ----
    __syncthreads();
    restage(acc, sA, wv, quad, l16);
    stageB8(Wt + 6 * 16384, sB, s, rr);
    __syncthreads();
    mfma8(sA, sB, acc, wv, quad, l16);
    biasrelu(acc, rb1, l16);
    // ---- phase 3: rec2 ----
    __syncthreads();
    restage(acc, sA, wv, quad, l16);
    stageB8(Wt + 7 * 16384, sB, s, rr);
    __syncthreads();
    mfma8(sA, sB, acc, wv, quad, l16);
    biasrelu(acc, rb2, l16);
    // ---- phase 4: rec3 (N=4, single 16-col tile) ----
    __syncthreads();
    restage(acc, sA, wv, quad, l16);
    {
        int n = rr;  // 16 B-rows only
        uint4 u = *(const uint4*)(Wt + 8 * 16384 + n * CH + 8 * s);
        *(uint4*)(&sB[n * CH + ((s ^ (n & 15)) * 8)]) = u;
    }
    __syncthreads();
    f32x4 a4[2];
    a4[0] = (f32x4){0.f, 0.f, 0.f, 0.f};
    a4[1] = (f32x4){0.f, 0.f, 0.f, 0.f};
    {
        const u16* pa0 = sA + (wv * 32 + l16) * CH;
        const u16* pa1 = pa0 + 16 * CH;
#pragma unroll
        for (int kc = 0; kc < 4; ++kc) {
            int off = (((kc << 2) | quad) ^ l16) << 3;
            s16x8 a0 = *(const s16x8*)(pa0 + off);
            s16x8 a1 = *(const s16x8*)(pa1 + off);
            s16x8 bfr = *(const s16x8*)(sB + l16 * CH + off);
            a4[0] = __builtin_amdgcn_mfma_f32_16x16x32_bf16(a0, bfr, a4[0], 0, 0, 0);
            a4[1] = __builtin_amdgcn_mfma_f32_16x16x32_bf16(a1, bfr, a4[1], 0, 0, 0);
        }
    }
    if (l16 < 4) {
        float bv = rb3[l16];
#pragma unroll
        for (int m = 0; m < 2; ++m)
#pragma unroll
            for (int r = 0; r < 4; ++r) {
                int row = r0 + wv * 32 + m * 16 + quad * 4 + r;
                if (row < NN) x_rec[(long)row * 4 + l16] = fmaxf(a4[m][r] + bv, 0.f);
            }
    }
}

// BN param: reduce pstats over NGB blocks. scale=g*rstd; shift=b-mu*g*rstd.
__global__ __launch_bounds__(256) void k_bnparam(const float* __restrict__ pstats,
                                                 const float* __restrict__ g,
                                                 const float* __restrict__ b,
                                                 float* __restrict__ scale,
                                                 float* __restrict__ shift) {
    __shared__ float sm[256];
    int t = threadIdx.x;
    float acc = 0.f;
    for (int blk = 0; blk < NGB; ++blk) acc += pstats[blk * 256 + t];
    sm[t] = acc;
    __syncthreads();
    if (t < 128) {
        float mu = sm[t] / (float)NN;
        float var = sm[128 + t] / (float)NN - mu * mu;
        float rstd = rsqrtf(var + 1e-5f);
        float gg = g[t], bb = b[t];
        scale[t] = gg * rstd;
        shift[t] = bb - mu * gg * rstd;
    }
}

// ---------------------------------------------------------------------------
// global_add_pool, parallel: 392 blocks x 128 rows; run-length accumulate in
// the sorted batch; one unsafeAtomicAdd per (run, channel, half).
// ---------------------------------------------------------------------------
__global__ __launch_bounds__(256) void k_pool(const u16* __restrict__ x,
                                              const int* __restrict__ batch,
                                              float* __restrict__ pooled) {
    int r0 = blockIdx.x * 128;
    if (r0 >= NN) return;
    int rend = r0 + 128 < NN ? r0 + 128 : NN;
    int c = threadIdx.x & 127;
    int half = threadIdx.x >> 7;
    int r = r0 + half;
    if (r >= rend) return;
    int g = batch[r];
    float s = 0.f;
    for (; r < rend; r += 2) {
        int gg = batch[r];
        if (gg != g) {
            unsafeAtomicAdd(pooled + g * CH + c, s);
            s = 0.f;
            g = gg;
        }
        s += b2f(x[(long)r * CH + c]);
    }
    unsafeAtomicAdd(pooled + g * CH + c, s);
}

// out[b] = relu(pooled[b] @ W1 + b1) @ W2 + b2  ; grid 64 x 128, all f32
__global__ __launch_bounds__(128) void k_mlp(const float* __restrict__ pooled,
                                             const float* __restrict__ W1,
                                             const float* __restrict__ b1,
                                             const float* __restrict__ W2,
                                             const float* __restrict__ b2,
                                             float* __restrict__ out) {
    __shared__ float p[128], t1[128];
    int b = blockIdx.x, t = threadIdx.x;
    p[t] = pooled[b * CH + t];
    __syncthreads();
    float acc = b1[t];
    for (int k = 0; k < 128; ++k) acc += p[k] * W1[k * 128 + t];
    t1[t] = fmaxf(acc, 0.f);
    __syncthreads();
    if (t < 64) {
        float o = b2[t];
        for (int k = 0; k < 128; ++k) o += t1[k] * W2[k * 64 + t];
        out[b * 64 + t] = o;
    }
}

// ---------------------------------------------------------------------------
extern "C" void kernel_launch(void* const* d_in, const int* in_sizes, int n_in,
                              void* d_out, int out_size, void* d_ws, size_t ws_size,
                              hipStream_t stream) {
    const float* x_in   = (const float*)d_in[0];
    const int*   ei     = (const int*)d_in[1];
    const int*   batch  = (const int*)d_in[2];
    const float* convW1 = (const float*)d_in[3];
    const float* convb1 = (const float*)d_in[4];
    const float* bn_g   = (const float*)d_in[5];
    const float* bn_b   = (const float*)d_in[6];
    const float* convW2 = (const float*)d_in[7];
    const float* convb2 = (const float*)d_in[8];
    const float* recW1  = (const float*)d_in[9];
    const float* recb1  = (const float*)d_in[10];
    const float* recW2  = (const float*)d_in[11];
    const float* recb2  = (const float*)d_in[12];
    const float* recW3  = (const float*)d_in[13];
    const float* recb3  = (const float*)d_in[14];
    const float* mlpW1  = (const float*)d_in[15];
    const float* mlpb1  = (const float*)d_in[16];
    const float* mlpW2  = (const float*)d_in[17];
    const float* mlpb2  = (const float*)d_in[18];

    float* out   = (float*)d_out;      // [64*64] out, then [50000*4] x_rec
    float* x_rec = out + 4096;

    char* w = (char*)d_ws;
    u16*   x16    = (u16*)w;    w += (size_t)NN * CH * 2;      // bf16 copy of x_in
    u16*   y16    = (u16*)w;    w += (size_t)NN * CH * 2;      // gather output (bf16)
    u16*   h16    = (u16*)w;    w += (size_t)NN * CH * 2;      // GEMM1 out (bf16)
    u16*   xc     = (u16*)w;    w += (size_t)NN * CH * 2;      // layer output (bf16)
    u16*   Wt     = (u16*)w;    w += (size_t)9 * 16384 * 2;    // transposed bf16 weights
    float* pstats = (float*)w;  w += (size_t)NGB * 256 * 4;    // fused BN partials
    float* scale  = (float*)w;  w += 128 * 4;
    float* shift  = (float*)w;  w += 128 * 4;
    float* pooled = (float*)w;  w += (size_t)BB * CH * 4;
    int*   deg    = (int*)w;    w += (size_t)NN * 4;
    int*   bsum   = (int*)w;    w += (size_t)NSB * 4;
    int*   rowptr = (int*)w;    w += (size_t)(NN + 1) * 4;
    int*   cur    = (int*)w;    w += (size_t)NN * 4;
    int*   perm   = (int*)w;    w += (size_t)EE * 4;

    dim3 b256(256), b128(128);

    // CSR build (parallel scan) + weight transpose + x->bf16 + pooled zero
    k_zero2<<<228, b256, 0, stream>>>(deg, pooled);
    k_count<<<2344, b256, 0, stream>>>(ei, deg);
    k_scanA<<<NSB, b256, 0, stream>>>(deg, bsum);
    k_scanB<<<NSB, b256, 0, stream>>>(deg, bsum, rowptr, cur);
    k_fill<<<2344, b256, 0, stream>>>(ei, cur, perm);
    k_cvt<<<3125, b256, 0, stream>>>(x_in, x16);
    k_transpose_all<<<576, b256, 0, stream>>>(convW1, convW2, recW1, recW2, recW3, Wt);

    const u16* cur_x = x16;
    for (int l = 0; l < LL; ++l) {
        k_gather<<<3125, b256, 0, stream>>>(cur_x, rowptr, perm, y16);
        // GEMM1: h = y @ W1 + b1 (bf16 A -> bf16 C), fused BN-stats partials
        k_gemm<true, false, false, true, true><<<NGB, b256, 0, stream>>>(
            y16, Wt + l * 16384, convb1 + l * 128, nullptr, nullptr, h16, pstats, NN);
        k_bnparam<<<1, b256, 0, stream>>>(pstats, bn_g + l * 128, bn_b + l * 128, scale, shift);
        if (l < LL - 1) {
            // GEMM2: xc = relu(relu(BN(h)) @ W2 + b2), BN fused
            k_gemm<true, true, true, false, true><<<NGB, b256, 0, stream>>>(
                h16, Wt + (3 + l) * 16384, convb2 + l * 128, scale, shift, xc, nullptr, NN);
            cur_x = xc;
        }
    }
    // fused: GEMM2(l=3) + rec1 + rec2 + rec3 (tile-resident chain)
    k_tail<<<NGB, b256, 0, stream>>>(h16, Wt, convb2 + 2 * 128, scale, shift,
                                     recb1, recb2, recb3, xc, x_rec);
    // pooling + final MLP
    k_pool<<<NPB, b256, 0, stream>>>(xc, batch, pooled);
    k_mlp<<<64, b128, 0, stream>>>(pooled, mlpW1, mlpb1, mlpW2, mlpb2, out);
}

// Round 10
// 425.386 us; speedup vs baseline: 4.6872x; 1.0147x over previous
//
#include <hip/hip_runtime.h>

#define NN 50000
#define EE 600000
#define BB 64
#define CH 128
#define LL 3
#define NGB 391   // GEMM/layer row-blocks = ceil(50000/128)
#define NSB 196   // scan blocks = ceil(50000/256)
#define NPB 392   // pool blocks = ceil(50000/128)

typedef unsigned short u16;
typedef unsigned int u32;
typedef short s16x8 __attribute__((ext_vector_type(8)));
typedef float f32x4 __attribute__((ext_vector_type(4)));

__device__ __forceinline__ u16 f2b(float f) {
    u32 x = __float_as_uint(f);
    return (u16)((x + 0x7FFFu + ((x >> 16) & 1u)) >> 16);  // RNE f32->bf16
}
__device__ __forceinline__ float b2f(u16 u) {
    return __uint_as_float(((u32)u) << 16);
}

// ---------------------------------------------------------------------------
// zero: deg[NN], pooled[BB*CH], gstats[3*256], bar[4]
// ---------------------------------------------------------------------------
__global__ __launch_bounds__(256) void k_zero2(int* __restrict__ deg,
                                               float* __restrict__ pooled,
                                               float* __restrict__ gstats,
                                               int* __restrict__ bar) {
    int i = blockIdx.x * 256 + threadIdx.x;
    if (i < NN) deg[i] = 0;
    int j = i - NN;
    if (j >= 0 && j < BB * CH) pooled[j] = 0.f;
    int k = j - BB * CH;
    if (k >= 0 && k < 3 * 256) gstats[k] = 0.f;
    int l = k - 3 * 256;
    if (l >= 0 && l < 4) bar[l] = 0;
}

__global__ __launch_bounds__(256) void k_count(const int* __restrict__ ei,
                                               int* __restrict__ deg) {
    int e = blockIdx.x * 256 + threadIdx.x;
    if (e < EE) atomicAdd(&deg[ei[EE + e]], 1);
}

// stage A: per-block (256 elems) sum of deg -> bsum[blk]
__global__ __launch_bounds__(256) void k_scanA(const int* __restrict__ deg,
                                               int* __restrict__ bsum) {
    __shared__ int sm[256];
    int i = blockIdx.x * 256 + threadIdx.x;
    sm[threadIdx.x] = (i < NN) ? deg[i] : 0;
    __syncthreads();
    for (int off = 128; off > 0; off >>= 1) {
        if (threadIdx.x < off) sm[threadIdx.x] += sm[threadIdx.x + off];
        __syncthreads();
    }
    if (threadIdx.x == 0) bsum[blockIdx.x] = sm[0];
}

// stage B: scan bsum in LDS -> block offset; local scan -> rowptr & cur
__global__ __launch_bounds__(256) void k_scanB(const int* __restrict__ deg,
                                               const int* __restrict__ bsum,
                                               int* __restrict__ rowptr,
                                               int* __restrict__ cur) {
    __shared__ int sb[256], sd[256];
    int t = threadIdx.x;
    sb[t] = (t < NSB) ? bsum[t] : 0;
    __syncthreads();
    for (int off = 1; off < 256; off <<= 1) {
        int v = (t >= off) ? sb[t - off] : 0;
        __syncthreads();
        sb[t] += v;
        __syncthreads();
    }
    int blockOff = (blockIdx.x == 0) ? 0 : sb[blockIdx.x - 1];
    int i = blockIdx.x * 256 + t;
    int d = (i < NN) ? deg[i] : 0;
    sd[t] = d;
    __syncthreads();
    for (int off = 1; off < 256; off <<= 1) {
        int v = (t >= off) ? sd[t - off] : 0;
        __syncthreads();
        sd[t] += v;
        __syncthreads();
    }
    int excl = blockOff + sd[t] - d;
    if (i < NN) { rowptr[i] = excl; cur[i] = excl; }
    if (i == NN - 1) rowptr[NN] = excl + d;
}

__global__ __launch_bounds__(256) void k_fill(const int* __restrict__ ei,
                                              int* __restrict__ cur,
                                              int* __restrict__ perm) {
    int e = blockIdx.x * 256 + threadIdx.x;
    if (e < EE) {
        int dst = ei[EE + e];
        int idx = atomicAdd(&cur[dst], 1);
        perm[idx] = ei[e];
    }
}

// x16 = bf16(x_in), 8 elements/thread. grid 3125 x 256.
__global__ __launch_bounds__(256) void k_cvt(const float* __restrict__ x,
                                             u16* __restrict__ y) {
    long base = (long)(blockIdx.x * 256 + threadIdx.x) * 8;
    if (base < (long)NN * CH) {
        float4 f0 = *(const float4*)(x + base);
        float4 f1 = *(const float4*)(x + base + 4);
        union { u16 pk[8]; uint4 v; } uu;
        uu.pk[0] = f2b(f0.x); uu.pk[1] = f2b(f0.y);
        uu.pk[2] = f2b(f0.z); uu.pk[3] = f2b(f0.w);
        uu.pk[4] = f2b(f1.x); uu.pk[5] = f2b(f1.y);
        uu.pk[6] = f2b(f1.z); uu.pk[7] = f2b(f1.w);
        *(uint4*)(y + base) = uu.v;
    }
}

// ---------------------------------------------------------------------------
// Gather: y[dst] = bf16( x[dst] + sum_{src} x[src] ), bf16 in, f32 accum.
// One dst per 16-lane group; 2-way unrolled edge loop.
// ---------------------------------------------------------------------------
__global__ __launch_bounds__(256) void k_gather(const u16* __restrict__ x,
                                                const int* __restrict__ rowptr,
                                                const int* __restrict__ perm,
                                                u16* __restrict__ y) {
    int dst = blockIdx.x * 16 + (threadIdx.x >> 4);
    if (dst >= NN) return;
    int lane = threadIdx.x & 15;
    int co = lane * 8;
    int beg = rowptr[dst], end = rowptr[dst + 1];
    union { u16 pk[8]; uint4 v; } uu;
    uu.v = *(const uint4*)(x + (long)dst * CH + co);
    float a[8], b[8];
#pragma unroll
    for (int j = 0; j < 8; ++j) { a[j] = b2f(uu.pk[j]); b[j] = 0.f; }
    int e = beg;
    for (; e + 1 < end; e += 2) {
        int s0 = perm[e], s1 = perm[e + 1];
        union { u16 pk[8]; uint4 v; } v0, v1;
        v0.v = *(const uint4*)(x + (long)s0 * CH + co);
        v1.v = *(const uint4*)(x + (long)s1 * CH + co);
#pragma unroll
        for (int j = 0; j < 8; ++j) { a[j] += b2f(v0.pk[j]); b[j] += b2f(v1.pk[j]); }
    }
    if (e < end) {
        int s0 = perm[e];
        union { u16 pk[8]; uint4 v; } v0;
        v0.v = *(const uint4*)(x + (long)s0 * CH + co);
#pragma unroll
        for (int j = 0; j < 8; ++j) a[j] += b2f(v0.pk[j]);
    }
    union { u16 pk[8]; uint4 v; } ov;
#pragma unroll
    for (int j = 0; j < 8; ++j) ov.pk[j] = f2b(a[j] + b[j]);
    *(uint4*)(y + (long)dst * CH + co) = ov.v;
}

// ---------------------------------------------------------------------------
// Transpose + convert weights once: Wt[slot][n*128+k] = bf16(W[k][n])
// slots 0-2: convW1[l], 3-5: convW2[l], 6: recW1, 7: recW2, 8: recW3 (zero-pad)
// ---------------------------------------------------------------------------
__global__ __launch_bounds__(256) void k_transpose_all(
    const float* __restrict__ cW1, const float* __restrict__ cW2,
    const float* __restrict__ rW1, const float* __restrict__ rW2,
    const float* __restrict__ rW3, u16* __restrict__ Wt) {
    int idx = blockIdx.x * 256 + threadIdx.x;
    if (idx < 8 * 16384) {
        int slot = idx >> 14;
        int wi = idx & 16383;
        int k = wi >> 7, n = wi & 127;
        const float* src = slot < 3 ? cW1 + slot * 16384
                         : slot < 6 ? cW2 + (slot - 3) * 16384
                         : slot == 6 ? rW1 : rW2;
        Wt[slot * 16384 + n * 128 + k] = f2b(src[wi]);
    } else if (idx < 9 * 16384) {
        int j = idx - 8 * 16384;
        int n = j >> 7, k = j & 127;
        Wt[8 * 16384 + j] = (n < 4) ? f2b(rW3[k * 4 + n]) : (u16)0;
    }
}

// ---------------------------------------------------------------------------
// Shared GEMM building blocks (layouts verified m89/m91; XOR-swizzle c^(r&15))
// ---------------------------------------------------------------------------
__device__ __forceinline__ void stageB8(const u16* __restrict__ Wt, u16* sB,
                                        int s, int rr) {
#pragma unroll
    for (int it = 0; it < 8; ++it) {
        int n = it * 16 + rr;
        uint4 u = *(const uint4*)(Wt + n * CH + 8 * s);
        *(uint4*)(&sB[n * CH + ((s ^ (n & 15)) * 8)]) = u;
    }
}

__device__ __forceinline__ void mfma8(const u16* sA, const u16* sB,
                                      f32x4 acc[2][8], int wv, int quad, int l16) {
    f32x4 z = {0.f, 0.f, 0.f, 0.f};
#pragma unroll
    for (int m = 0; m < 2; ++m)
#pragma unroll
        for (int t = 0; t < 8; ++t) acc[m][t] = z;
    const u16* pa0 = sA + (wv * 32 + l16) * CH;
    const u16* pa1 = pa0 + 16 * CH;
#pragma unroll
    for (int kc = 0; kc < 4; ++kc) {
        int off = (((kc << 2) | quad) ^ l16) << 3;
        s16x8 a0 = *(const s16x8*)(pa0 + off);
        s16x8 a1 = *(const s16x8*)(pa1 + off);
#pragma unroll
        for (int t = 0; t < 8; ++t) {
            s16x8 bfr = *(const s16x8*)(sB + (t * 16 + l16) * CH + off);
            acc[0][t] = __builtin_amdgcn_mfma_f32_16x16x32_bf16(a0, bfr, acc[0][t], 0, 0, 0);
            acc[1][t] = __builtin_amdgcn_mfma_f32_16x16x32_bf16(a1, bfr, acc[1][t], 0, 0, 0);
        }
    }
}

__device__ __forceinline__ void biasrelu(f32x4 acc[2][8],
                                         const float* __restrict__ bias, int l16) {
#pragma unroll
    for (int t = 0; t < 8; ++t) {
        float bv = bias[t * 16 + l16];
#pragma unroll
        for (int m = 0; m < 2; ++m)
#pragma unroll
            for (int r = 0; r < 4; ++r)
                acc[m][t][r] = fmaxf(acc[m][t][r] + bv, 0.f);
    }
}

// write C tile (in acc) back into sA as bf16 with the A-read XOR-swizzle.
__device__ __forceinline__ void restage(const f32x4 acc[2][8], u16* sA,
                                        int wv, int quad, int l16) {
#pragma unroll
    for (int t = 0; t < 8; ++t) {
        int chunk = (t << 1) | (l16 >> 3);
        int o7 = l16 & 7;
#pragma unroll
        for (int m = 0; m < 2; ++m)
#pragma unroll
            for (int r = 0; r < 4; ++r) {
                int lr = wv * 32 + m * 16 + quad * 4 + r;
                sA[lr * CH + ((chunk ^ (lr & 15)) << 3) + o7] = f2b(acc[m][t][r]);
            }
    }
}

// manual grid barrier: all NGB blocks are co-resident (2 blocks/CU x 256 CUs
// = 512 slots >= 391, guaranteed by __launch_bounds__(256,2) + 64KB LDS).
__device__ __forceinline__ void grid_barrier(int* bar, int tid) {
    __syncthreads();
    if (tid == 0) {
        __hip_atomic_fetch_add(bar, 1, __ATOMIC_ACQ_REL, __HIP_MEMORY_SCOPE_AGENT);
        while (__hip_atomic_load(bar, __ATOMIC_ACQUIRE, __HIP_MEMORY_SCOPE_AGENT) < NGB) {
            __builtin_amdgcn_s_sleep(8);
        }
    }
    __syncthreads();
}

// ---------------------------------------------------------------------------
// Fused per-layer kernel (regular launch + manual grid barrier):
//   h = y@W1 + b1 (kept in regs, f32); block stat partials -> atomicAdd gstats
//   grid_barrier ; scale/shift from gstats ; acc = relu(BN(h))
//   restage -> GEMM2: xc = relu(acc@W2 + b2)
//   LAST: tile-resident rec1/rec2/rec3 -> x_rec.
// ---------------------------------------------------------------------------
template <bool LAST>
__global__ __launch_bounds__(256, 2) void k_layer(
    const u16* __restrict__ y16, const u16* __restrict__ Wt, int layer,
    const float* __restrict__ cb1, const float* __restrict__ cb2,
    const float* __restrict__ g, const float* __restrict__ bbeta,
    float* __restrict__ gstats, int* __restrict__ bar, u16* __restrict__ xc,
    const float* __restrict__ rb1, const float* __restrict__ rb2,
    const float* __restrict__ rb3, float* __restrict__ x_rec) {
    __shared__ u16 sA[128 * CH];
    __shared__ u16 sB[128 * CH];
    const int tid = threadIdx.x;
    const int s = tid & 15, rr = tid >> 4;
    const int r0 = blockIdx.x * 128;
    const int lane = tid & 63, wv = tid >> 6, quad = lane >> 4, l16 = lane & 15;

    // ---- phase 1: GEMM1 ----
    stageB8(Wt + layer * 16384, sB, s, rr);
#pragma unroll
    for (int it = 0; it < 8; ++it) {
        int lr = it * 16 + rr, gr = r0 + lr;
        union { u16 pk[8]; uint4 v; } uu;
        if (gr < NN) {
            uu.v = *(const uint4*)(y16 + (long)gr * CH + 8 * s);
        } else {
#pragma unroll
            for (int j = 0; j < 8; ++j) uu.pk[j] = 0;
        }
        *(uint4*)(&sA[lr * CH + ((s ^ (lr & 15)) * 8)]) = uu.v;
    }
    __syncthreads();
    f32x4 acc[2][8];
    mfma8(sA, sB, acc, wv, quad, l16);

    // bias add (h pre-relu kept in acc) + stats over valid rows
    float ss[8], qq[8];
#pragma unroll
    for (int t = 0; t < 8; ++t) {
        float bv = cb1[t * 16 + l16];
        ss[t] = 0.f; qq[t] = 0.f;
#pragma unroll
        for (int m = 0; m < 2; ++m) {
            int rbase = r0 + wv * 32 + m * 16 + quad * 4;
#pragma unroll
            for (int r = 0; r < 4; ++r) {
                float v = acc[m][t][r] + bv;
                acc[m][t][r] = v;
                if (rbase + r < NN) { ss[t] += v; qq[t] += v * v; }
            }
        }
    }
#pragma unroll
    for (int t = 0; t < 8; ++t) {
        ss[t] += __shfl_xor(ss[t], 16);
        ss[t] += __shfl_xor(ss[t], 32);
        qq[t] += __shfl_xor(qq[t], 16);
        qq[t] += __shfl_xor(qq[t], 32);
    }
    float* red = (float*)sA;
    __syncthreads();
    if (lane < 16) {
#pragma unroll
        for (int t = 0; t < 8; ++t) {
            red[wv * 256 + t * 16 + l16] = ss[t];
            red[wv * 256 + 128 + t * 16 + l16] = qq[t];
        }
    }
    __syncthreads();
    unsafeAtomicAdd(&gstats[tid],
                    red[tid] + red[256 + tid] + red[512 + tid] + red[768 + tid]);

    grid_barrier(bar, tid);

    // ---- BN apply in regs (coherent reads of gstats) ----
#pragma unroll
    for (int t = 0; t < 8; ++t) {
        int col = t * 16 + l16;
        float sum = __hip_atomic_load(&gstats[col], __ATOMIC_RELAXED,
                                      __HIP_MEMORY_SCOPE_AGENT);
        float sq = __hip_atomic_load(&gstats[128 + col], __ATOMIC_RELAXED,
                                     __HIP_MEMORY_SCOPE_AGENT);
        float mu = sum / (float)NN;
        float var = sq / (float)NN - mu * mu;
        float rstd = rsqrtf(var + 1e-5f);
        float sc = g[col] * rstd;
        float sh = bbeta[col] - mu * sc;
#pragma unroll
        for (int m = 0; m < 2; ++m)
#pragma unroll
            for (int r = 0; r < 4; ++r)
                acc[m][t][r] = fmaxf(acc[m][t][r] * sc + sh, 0.f);
    }

    // ---- phase 2: GEMM2 ----
    __syncthreads();  // all waves done with red[] (sA) before restage
    restage(acc, sA, wv, quad, l16);
    stageB8(Wt + (3 + layer) * 16384, sB, s, rr);
    __syncthreads();
    mfma8(sA, sB, acc, wv, quad, l16);
    biasrelu(acc, cb2, l16);
#pragma unroll
    for (int t = 0; t < 8; ++t) {
        int col = t * 16 + l16;
#pragma unroll
        for (int m = 0; m < 2; ++m)
#pragma unroll
            for (int r = 0; r < 4; ++r) {
                int row = r0 + wv * 32 + m * 16 + quad * 4 + r;
                if (row < NN) xc[(long)row * CH + col] = f2b(acc[m][t][r]);
            }
    }

    if constexpr (LAST) {
        // ---- rec1 ----
        __syncthreads();
        restage(acc, sA, wv, quad, l16);
        stageB8(Wt + 6 * 16384, sB, s, rr);
        __syncthreads();
        mfma8(sA, sB, acc, wv, quad, l16);
        biasrelu(acc, rb1, l16);
        // ---- rec2 ----
        __syncthreads();
        restage(acc, sA, wv, quad, l16);
        stageB8(Wt + 7 * 16384, sB, s, rr);
        __syncthreads();
        mfma8(sA, sB, acc, wv, quad, l16);
        biasrelu(acc, rb2, l16);
        // ---- rec3 (N=4, one 16-col tile) ----
        __syncthreads();
        restage(acc, sA, wv, quad, l16);
        {
            int n = rr;  // 16 B-rows
            uint4 u = *(const uint4*)(Wt + 8 * 16384 + n * CH + 8 * s);
            *(uint4*)(&sB[n * CH + ((s ^ (n & 15)) * 8)]) = u;
        }
        __syncthreads();
        f32x4 a4[2];
        a4[0] = (f32x4){0.f, 0.f, 0.f, 0.f};
        a4[1] = (f32x4){0.f, 0.f, 0.f, 0.f};
        const u16* pa0 = sA + (wv * 32 + l16) * CH;
        const u16* pa1 = pa0 + 16 * CH;
#pragma unroll
        for (int kc = 0; kc < 4; ++kc) {
            int off = (((kc << 2) | quad) ^ l16) << 3;
            s16x8 a0 = *(const s16x8*)(pa0 + off);
            s16x8 a1 = *(const s16x8*)(pa1 + off);
            s16x8 bfr = *(const s16x8*)(sB + l16 * CH + off);
            a4[0] = __builtin_amdgcn_mfma_f32_16x16x32_bf16(a0, bfr, a4[0], 0, 0, 0);
            a4[1] = __builtin_amdgcn_mfma_f32_16x16x32_bf16(a1, bfr, a4[1], 0, 0, 0);
        }
        if (l16 < 4) {
            float bv = rb3[l16];
#pragma unroll
            for (int m = 0; m < 2; ++m)
#pragma unroll
                for (int r = 0; r < 4; ++r) {
                    int row = r0 + wv * 32 + m * 16 + quad * 4 + r;
                    if (row < NN) x_rec[(long)row * 4 + l16] = fmaxf(a4[m][r] + bv, 0.f);
                }
        }
    }
}

// ---------------------------------------------------------------------------
// global_add_pool, parallel: 392 blocks x 128 rows; run-length accumulate.
// ---------------------------------------------------------------------------
__global__ __launch_bounds__(256) void k_pool(const u16* __restrict__ x,
                                              const int* __restrict__ batch,
                                              float* __restrict__ pooled) {
    int r0 = blockIdx.x * 128;
    if (r0 >= NN) return;
    int rend = r0 + 128 < NN ? r0 + 128 : NN;
    int c = threadIdx.x & 127;
    int half = threadIdx.x >> 7;
    int r = r0 + half;
    if (r >= rend) return;
    int g = batch[r];
    float s = 0.f;
    for (; r < rend; r += 2) {
        int gg = batch[r];
        if (gg != g) {
            unsafeAtomicAdd(pooled + g * CH + c, s);
            s = 0.f;
            g = gg;
        }
        s += b2f(x[(long)r * CH + c]);
    }
    unsafeAtomicAdd(pooled + g * CH + c, s);
}

// out[b] = relu(pooled[b] @ W1 + b1) @ W2 + b2  ; grid 64 x 128, all f32
__global__ __launch_bounds__(128) void k_mlp(const float* __restrict__ pooled,
                                             const float* __restrict__ W1,
                                             const float* __restrict__ b1,
                                             const float* __restrict__ W2,
                                             const float* __restrict__ b2,
                                             float* __restrict__ out) {
    __shared__ float p[128], t1[128];
    int b = blockIdx.x, t = threadIdx.x;
    p[t] = pooled[b * CH + t];
    __syncthreads();
    float acc = b1[t];
    for (int k = 0; k < 128; ++k) acc += p[k] * W1[k * 128 + t];
    t1[t] = fmaxf(acc, 0.f);
    __syncthreads();
    if (t < 64) {
        float o = b2[t];
        for (int k = 0; k < 128; ++k) o += t1[k] * W2[k * 64 + t];
        out[b * 64 + t] = o;
    }
}

// ---------------------------------------------------------------------------
extern "C" void kernel_launch(void* const* d_in, const int* in_sizes, int n_in,
                              void* d_out, int out_size, void* d_ws, size_t ws_size,
                              hipStream_t stream) {
    const float* x_in   = (const float*)d_in[0];
    const int*   ei     = (const int*)d_in[1];
    const int*   batch  = (const int*)d_in[2];
    const float* convW1 = (const float*)d_in[3];
    const float* convb1 = (const float*)d_in[4];
    const float* bn_g   = (const float*)d_in[5];
    const float* bn_b   = (const float*)d_in[6];
    const float* convW2 = (const float*)d_in[7];
    const float* convb2 = (const float*)d_in[8];
    const float* recW1  = (const float*)d_in[9];
    const float* recb1  = (const float*)d_in[10];
    const float* recW2  = (const float*)d_in[11];
    const float* recb2  = (const float*)d_in[12];
    const float* recW3  = (const float*)d_in[13];
    const float* recb3  = (const float*)d_in[14];
    const float* mlpW1  = (const float*)d_in[15];
    const float* mlpb1  = (const float*)d_in[16];
    const float* mlpW2  = (const float*)d_in[17];
    const float* mlpb2  = (const float*)d_in[18];

    float* out   = (float*)d_out;      // [64*64] out, then [50000*4] x_rec
    float* x_rec = out + 4096;

    char* w = (char*)d_ws;
    u16*   x16    = (u16*)w;    w += (size_t)NN * CH * 2;      // bf16 copy of x_in
    u16*   y16    = (u16*)w;    w += (size_t)NN * CH * 2;      // gather output
    u16*   xc     = (u16*)w;    w += (size_t)NN * CH * 2;      // layer output
    u16*   Wt     = (u16*)w;    w += (size_t)9 * 16384 * 2;    // transposed bf16 weights
    float* gstats = (float*)w;  w += (size_t)3 * 256 * 4;      // BN sums per layer
    int*   bar    = (int*)w;    w += 4 * 4;                    // grid barriers
    float* pooled = (float*)w;  w += (size_t)BB * CH * 4;
    int*   deg    = (int*)w;    w += (size_t)NN * 4;
    int*   bsum   = (int*)w;    w += (size_t)NSB * 4;
    int*   rowptr = (int*)w;    w += (size_t)(NN + 1) * 4;
    int*   cur    = (int*)w;    w += (size_t)NN * 4;
    int*   perm   = (int*)w;    w += (size_t)EE * 4;

    dim3 b256(256), b128(128);

    // CSR build + weight transpose + x->bf16 + zeroing
    k_zero2<<<231, b256, 0, stream>>>(deg, pooled, gstats, bar);
    k_count<<<2344, b256, 0, stream>>>(ei, deg);
    k_scanA<<<NSB, b256, 0, stream>>>(deg, bsum);
    k_scanB<<<NSB, b256, 0, stream>>>(deg, bsum, rowptr, cur);
    k_fill<<<2344, b256, 0, stream>>>(ei, cur, perm);
    k_cvt<<<3125, b256, 0, stream>>>(x_in, x16);
    k_transpose_all<<<576, b256, 0, stream>>>(convW1, convW2, recW1, recW2, recW3, Wt);

    const u16* cur_x = x16;
    for (int l = 0; l < LL; ++l) {
        k_gather<<<3125, b256, 0, stream>>>(cur_x, rowptr, perm, y16);
        if (l < LL - 1)
            k_layer<false><<<NGB, b256, 0, stream>>>(
                y16, Wt, l, convb1 + l * 128, convb2 + l * 128,
                bn_g + l * 128, bn_b + l * 128, gstats + l * 256, bar + l, xc,
                recb1, recb2, recb3, x_rec);
        else
            k_layer<true><<<NGB, b256, 0, stream>>>(
                y16, Wt, l, convb1 + l * 128, convb2 + l * 128,
                bn_g + l * 128, bn_b + l * 128, gstats + l * 256, bar + l, xc,
                recb1, recb2, recb3, x_rec);
        cur_x = xc;
    }
    // pooling + final MLP
    k_pool<<<NPB, b256, 0, stream>>>(xc, batch, pooled);
    k_mlp<<<64, b128, 0, stream>>>(pooled, mlpW1, mlpb1, mlpW2, mlpb2, out);
}